// Round 1
// 4685.733 us; speedup vs baseline: 1.3378x; 1.3378x over previous
//
#include <hip/hip_runtime.h>
#include <hip/hip_bf16.h>

// LowRankNextCharacterLSTM on MI355X (gfx950). Inputs fp32 (runtime-detected,
// canonicalized to bf16); output fp32 (mode-matched store).
//
// Algebra: R_GATE == HIDDEN -> fold W = U@VT ([4096,1024]),
// b = bU_ih + bU_hh + bVT_ih@U_ih^T + bVT_hh@U_hh^T; then
//   gates = x @ W_ih^T + h @ W_hh^T + b.
// Recurrence: ONE persistent kernel, 256 WGs (1 block/CU via 137KB LDS),
// weights staged to LDS once, two layers pipelined, 257 grid barriers.
//
// Round 9: H reads switched from LLC-bypass 8B atomics (latency/concurrency
// bound: ~48MB/step of uncached 8B LLC requests ~= 2 TB/s ~= 20us/step) to
// PLAIN L2-CACHED loads. Coherence by address freshness:
//   - every H tile is written to a t-unique address (H2 was already [t];
//     H1 becomes [256][64][1024] = 32MB when ws_size >= 100MB, else falls
//     back to the old 4-deep ring + bypass loads),
//   - producers store write-through (sc0 sc1) and drain before the arrival
//     flag, so the LLC holds the data before any reader can miss-fetch it,
//   - a fresh line can therefore never be stale in any XCD's L1/L2,
//   - cross-launch staleness is covered by dispatch-boundary acquire/release
//     (already relied upon for Wc: cached stores in k_combine, cached loads
//     in k_lstm).
// Barrier: unchanged symmetric all-poll-all on 256 packed arrival slots.

#define B_SZ   64
#define T_SEQ  256
#define HID    1024
#define G4     4096

typedef __attribute__((ext_vector_type(8))) short bf16x8;
typedef __attribute__((ext_vector_type(4))) float f32x4;
typedef __attribute__((ext_vector_type(4))) short bf16x4;
typedef unsigned long long u64;

__device__ __forceinline__ f32x4 mfma16(bf16x8 a, bf16x8 b, f32x4 c) {
  return __builtin_amdgcn_mfma_f32_16x16x32_bf16(a, b, c, 0, 0, 0);
}
__device__ __forceinline__ float sigm(float x)  { return 1.f / (1.f + __expf(-x)); }
__device__ __forceinline__ float tanh_(float x) { return 2.f / (1.f + __expf(-2.f * x)) - 1.f; }
__device__ __forceinline__ f32x4 fzero() { f32x4 z; z[0]=0.f; z[1]=0.f; z[2]=0.f; z[3]=0.f; return z; }

// L2-bypass (agent-coherent) 16B load as 2x64-bit relaxed atomics
__device__ __forceinline__ bf16x8 lda(const __hip_bfloat16* p) {
  const u64* q = (const u64*)p;
  union { u64 u[2]; bf16x8 v; } r;
  r.u[0] = __hip_atomic_load(q,     __ATOMIC_RELAXED, __HIP_MEMORY_SCOPE_AGENT);
  r.u[1] = __hip_atomic_load(q + 1, __ATOMIC_RELAXED, __HIP_MEMORY_SCOPE_AGENT);
  return r.v;
}

// mode: 1 = inputs stored fp32, 0 = bf16
__device__ __forceinline__ float ld1(const void* p, size_t i, int mode) {
  return mode ? ((const float*)p)[i]
              : __bfloat162float(((const __hip_bfloat16*)p)[i]);
}
__device__ __forceinline__ bf16x8 ld8(const void* p, size_t i, int mode) {
  if (mode) {
    const float* f = (const float*)p + i;
    float4 a = *(const float4*)f;
    float4 b = *(const float4*)(f + 4);
    union { bf16x8 v; __hip_bfloat16 h[8]; } u;
    u.h[0] = __float2bfloat16(a.x); u.h[1] = __float2bfloat16(a.y);
    u.h[2] = __float2bfloat16(a.z); u.h[3] = __float2bfloat16(a.w);
    u.h[4] = __float2bfloat16(b.x); u.h[5] = __float2bfloat16(b.y);
    u.h[6] = __float2bfloat16(b.z); u.h[7] = __float2bfloat16(b.w);
    return u.v;
  }
  return *(const bf16x8*)((const __hip_bfloat16*)p + i);
}

// ---------------------------------------------------------------------------
__global__ void k_detect(const unsigned short* __restrict__ e, int* __restrict__ flags) {
  __shared__ int cnt;
  if (threadIdx.x == 0) cnt = 0;
  __syncthreads();
  int c = 0;
  for (int i = threadIdx.x; i < 2048; i += 256) {
    unsigned int bits = ((unsigned int)e[2 * i]) << 16;
    float f = __uint_as_float(bits);
    if (!isfinite(f) || fabsf(f) > 1e10f) ++c;
  }
  atomicAdd(&cnt, c);
  __syncthreads();
  if (threadIdx.x == 0) flags[0] = (cnt > 8) ? 1 : 0;
}

__global__ void k_cvt_b(const void* __restrict__ src, __hip_bfloat16* __restrict__ dst,
                        int n, const int* __restrict__ flags) {
  const int mode = flags[0];
  for (int i = blockIdx.x * blockDim.x + threadIdx.x; i < n; i += gridDim.x * blockDim.x)
    dst[i] = mode ? __float2bfloat16(((const float*)src)[i])
                  : ((const __hip_bfloat16*)src)[i];
}
__global__ void k_cvt_f(const void* __restrict__ src, float* __restrict__ dst,
                        int n, const int* __restrict__ flags) {
  const int mode = flags[0];
  for (int i = blockIdx.x * blockDim.x + threadIdx.x; i < n; i += gridDim.x * blockDim.x)
    dst[i] = mode ? ((const float*)src)[i]
                  : __bfloat162float(((const __hip_bfloat16*)src)[i]);
}

// zero the 256 packed arrival slots
__global__ void k_init(unsigned* bar) {
  bar[threadIdx.x] = 0u;
}

// ---------------------------------------------------------------------------
// K2: Wc[Mid] = U @ VT  (Mid = L*2+typ; typ 0=ih 1=hh), bf16 out, f32 acc
// ---------------------------------------------------------------------------
__global__ void __launch_bounds__(256) k_combine(
    const void* __restrict__ U_ih, const void* __restrict__ U_hh,
    const void* __restrict__ VT_ih, const void* __restrict__ VT_hh,
    __hip_bfloat16* __restrict__ Wc, const int* __restrict__ flags)
{
  __shared__ __hip_bfloat16 sB[4 * 64 * 8];
  const int mode = flags[0];
  const int idx  = blockIdx.x;
  const int Mid  = idx >> 10;
  const int rem  = idx & 1023;
  const int gblk = rem >> 4, kblk = rem & 15;
  const int L = Mid >> 1, typ = Mid & 1;
  const void* U  = typ ? U_hh  : U_ih;
  const void* VT = typ ? VT_hh : VT_ih;
  const size_t Uoff  = (size_t)L * G4 * HID;
  const size_t VToff = (size_t)L * HID * HID;
  const int tid = threadIdx.x, lane = tid & 63, wv = tid >> 6;

  f32x4 acc[4];
  for (int i = 0; i < 4; ++i) acc[i] = fzero();

  const int r_local = tid >> 3;
  const int kk8     = (tid & 7) * 8;

  for (int r0 = 0; r0 < HID; r0 += 32) {
    union { bf16x8 v; __hip_bfloat16 h[8]; } u;
    u.v = ld8(VT, VToff + (size_t)(r0 + r_local) * HID + kblk * 64 + kk8, mode);
    __syncthreads();
    #pragma unroll
    for (int j = 0; j < 8; ++j) {
      int k_local = kk8 + j;
      int tile = k_local >> 4;
      int ln   = ((r_local >> 3) << 4) | (k_local & 15);
      sB[(tile * 64 + ln) * 8 + (r_local & 7)] = u.h[j];
    }
    __syncthreads();
    bf16x8 a = ld8(U, Uoff + (size_t)(gblk * 64 + wv * 16 + (lane & 15)) * HID
                          + r0 + (lane >> 4) * 8, mode);
    #pragma unroll
    for (int nt = 0; nt < 4; ++nt) {
      bf16x8 b = *(const bf16x8*)(sB + (nt * 64 + lane) * 8);
      acc[nt] = mfma16(a, b, acc[nt]);
    }
  }
  #pragma unroll
  for (int nt = 0; nt < 4; ++nt)
    #pragma unroll
    for (int r = 0; r < 4; ++r) {
      int g = gblk * 64 + wv * 16 + (lane >> 4) * 4 + r;
      int k = kblk * 64 + nt * 16 + (lane & 15);
      Wc[((size_t)Mid * G4 + g) * HID + k] = __float2bfloat16(acc[nt][r]);
    }
}

// ---------------------------------------------------------------------------
// K3: bc[L][g] = bU_ih + bU_hh + bVT_ih@U_ih^T + bVT_hh@U_hh^T   (f32)
// ---------------------------------------------------------------------------
__global__ void __launch_bounds__(256) k_bias(
    const void* __restrict__ bVT_ih, const void* __restrict__ U_ih,
    const void* __restrict__ bU_ih,
    const void* __restrict__ bVT_hh, const void* __restrict__ U_hh,
    const void* __restrict__ bU_hh,
    float* __restrict__ bc, const int* __restrict__ flags)
{
  const int mode  = flags[0];
  const int g_all = blockIdx.x * 4 + (threadIdx.x >> 6);
  const int lane  = threadIdx.x & 63;
  const int L = g_all >> 12, g = g_all & 4095;
  const size_t ub = (size_t)(L * G4 + g) * HID + lane * 16;
  const size_t vb = (size_t)L * HID + lane * 16;
  float s = 0.f;
  #pragma unroll
  for (int c = 0; c < 16; ++c)
    s += ld1(bVT_ih, vb + c, mode) * ld1(U_ih, ub + c, mode)
       + ld1(bVT_hh, vb + c, mode) * ld1(U_hh, ub + c, mode);
  for (int off = 32; off; off >>= 1) s += __shfl_down(s, off);
  if (lane == 0)
    bc[g_all] = s + ld1(bU_ih, L * G4 + g, mode) + ld1(bU_hh, L * G4 + g, mode);
}

// ---------------------------------------------------------------------------
// K4: persistent pipelined LSTM. 256 WGs; WG w: L=w>>7, jg=w&127 (h cols
// [8jg,8jg+8)). Weights in LDS once (B-frag order). waves 0,1 = x-path,
// waves 2,3 = h-path. Macro-step s: L0 does t=s, L1 does t=s-1.
// cmode=1: H1/H2 reads are plain L2-cached loads (t-unique addresses keep
// them coherent). cmode=0: legacy bypass-atomic reads of the 4-deep H1 ring.
// ---------------------------------------------------------------------------
__global__ void __launch_bounds__(256, 1) k_lstm(
    const int* __restrict__ tokens, const __hip_bfloat16* __restrict__ embedC,
    const __hip_bfloat16* __restrict__ Wc, const float* __restrict__ bc,
    __hip_bfloat16* __restrict__ H1, __hip_bfloat16* __restrict__ H2,
    unsigned* bar, const int h1mask, const int cmode)
{
  extern __shared__ char smem[];
  __hip_bfloat16* Wl = (__hip_bfloat16*)smem;            // 128KB, B-frag order
  f32x4* Xex = (f32x4*)(smem + 131072);                  // 8KB exchange
  __hip_bfloat16* Hs = (__hip_bfloat16*)(smem + 139264); // 1KB h staging [64][8]

  const int tid  = threadIdx.x;
  const int lane = tid & 63, wv = tid >> 6;
  const int w    = blockIdx.x;
  const int L    = w >> 7, jg = w & 127;
  const int mat  = wv >> 1, mhalf = wv & 1;         // 0 = x-path, 1 = h-path
  const u64* arr64 = (const u64*)bar;

  // stage weight slices into LDS once; slot q = [mat(1)][ks(5)][tile(1)][ln(6)]
  for (int q = tid; q < 8192; q += 256) {
    int m_ = q >> 12, ks = (q >> 7) & 31, tl = (q >> 6) & 1, ln = q & 63;
    int n_local = tl * 16 + (ln & 15);
    int g = (n_local >> 3) * 1024 + jg * 8 + (n_local & 7);
    int k = ks * 32 + (ln >> 4) * 8;
    *(bf16x8*)(Wl + (size_t)q * 8) =
        *(const bf16x8*)(Wc + (((size_t)(L * 2 + m_) * G4 + g) << 10) + k);
  }
  const int nb = lane & 7;
  const float b_i = bc[L * G4 +        jg * 8 + nb];
  const float b_f = bc[L * G4 + 1024 + jg * 8 + nb];
  const float b_g = bc[L * G4 + 2048 + jg * 8 + nb];
  const float b_o = bc[L * G4 + 3072 + jg * 8 + nb];
  __syncthreads();

  float cst[2][4] = {{0.f,0.f,0.f,0.f},{0.f,0.f,0.f,0.f}};
  const int m0 = mhalf * 32 + (lane & 15);
  const int ko = (lane >> 4) * 8;
  const __hip_bfloat16* wbase = Wl + mat * 32768;
  unsigned gen = 0;

  for (int s = 0; s <= T_SEQ; ++s) {
    const int t = s - L;
    const bool act = (t >= 0 && t < T_SEQ);          // block-uniform
    if (act) {
      f32x4 acc00 = fzero(), acc01 = fzero(), acc10 = fzero(), acc11 = fzero();
      bool doGemm = true, cached = false;
      const __hip_bfloat16 *A0 = nullptr, *A1 = nullptr;
      if (mat == 0) {
        if (L == 0) {                                // embed: read-only, cached
          A0 = embedC + ((size_t)tokens[m0 * T_SEQ + t] << 10);
          A1 = embedC + ((size_t)tokens[(m0 + 16) * T_SEQ + t] << 10);
          cached = true;
        } else {                                     // H1[t]: fresh address
          A0 = H1 + ((((size_t)(t & h1mask)) * 64 + m0) << 10);
          A1 = A0 + ((size_t)16 << 10);
          cached = (cmode != 0);
        }
      } else {
        if (t == 0) doGemm = false;                  // h_{-1} = 0
        else {
          if (L == 0) {                              // H1[t-1]: fresh address
            A0 = H1 + ((((size_t)((t - 1) & h1mask)) * 64 + m0) << 10);
            cached = (cmode != 0);
          } else {                                   // H2[t-1]: always t-unique
            A0 = H2 + (((size_t)(t - 1) * 64 + m0) << 10);
            cached = true;
          }
          A1 = A0 + ((size_t)16 << 10);
        }
      }
      if (doGemm) {
        if (cached) {
          #pragma unroll 8
          for (int ks = 0; ks < 32; ++ks) {
            bf16x8 a0 = *(const bf16x8*)(A0 + ks * 32 + ko);
            bf16x8 a1 = *(const bf16x8*)(A1 + ks * 32 + ko);
            bf16x8 b0 = *(const bf16x8*)(wbase + (ks * 2 + 0) * 512 + lane * 8);
            bf16x8 b1 = *(const bf16x8*)(wbase + (ks * 2 + 1) * 512 + lane * 8);
            acc00 = mfma16(a0, b0, acc00);
            acc01 = mfma16(a0, b1, acc01);
            acc10 = mfma16(a1, b0, acc10);
            acc11 = mfma16(a1, b1, acc11);
          }
        } else {
          #pragma unroll 4
          for (int ks = 0; ks < 32; ++ks) {
            bf16x8 a0 = lda(A0 + ks * 32 + ko);
            bf16x8 a1 = lda(A1 + ks * 32 + ko);
            bf16x8 b0 = *(const bf16x8*)(wbase + (ks * 2 + 0) * 512 + lane * 8);
            bf16x8 b1 = *(const bf16x8*)(wbase + (ks * 2 + 1) * 512 + lane * 8);
            acc00 = mfma16(a0, b0, acc00);
            acc01 = mfma16(a0, b1, acc01);
            acc10 = mfma16(a1, b0, acc10);
            acc11 = mfma16(a1, b1, acc11);
          }
        }
      }
      if (mat == 0) {
        Xex[(mhalf * 4 + 0) * 64 + lane] = acc00;
        Xex[(mhalf * 4 + 1) * 64 + lane] = acc01;
        Xex[(mhalf * 4 + 2) * 64 + lane] = acc10;
        Xex[(mhalf * 4 + 3) * 64 + lane] = acc11;
      }
      __syncthreads();
      if (mat == 1) {                                // gates -> c,h -> LDS tile
        #pragma unroll
        for (int mt = 0; mt < 2; ++mt) {
          f32x4 aT0 = mt ? acc10 : acc00;
          f32x4 aT1 = mt ? acc11 : acc01;
          f32x4 gx0 = Xex[(mhalf * 4 + mt * 2 + 0) * 64 + lane];
          f32x4 gx1 = Xex[(mhalf * 4 + mt * 2 + 1) * 64 + lane];
          #pragma unroll
          for (int r = 0; r < 4; ++r) {
            float v0 = aT0[r] + gx0[r];
            float v1 = aT1[r] + gx1[r];
            float p0 = __shfl_xor(v0, 8);
            float p1 = __shfl_xor(v1, 8);
            if ((lane & 15) < 8) {
              float iv = sigm(v0 + b_i);
              float fv = sigm(p0 + b_f);
              float gv = tanh_(v1 + b_g);
              float ov = sigm(p1 + b_o);
              float c  = fv * cst[mt][r] + iv * gv;
              cst[mt][r] = c;
              float h  = ov * tanh_(c);
              int m = mhalf * 32 + mt * 16 + (lane >> 4) * 4 + r;
              Hs[m * 8 + (lane & 15)] = __float2bfloat16(h);
            }
          }
        }
      }
      __syncthreads();                               // Hs tile complete
      // flush Hs -> global as 8B agent-coherent (write-through) stores
      if (tid < 128) {
        char* HoutB = (L == 0) ? (char*)(H1 + (((size_t)(t & h1mask)) << 16))
                               : (char*)(H2 + (((size_t)t) << 16));
        u64 v = ((const u64*)Hs)[tid];
        u64* dst = (u64*)(HoutB + ((size_t)(tid >> 1) << 11) + (jg << 4) + ((tid & 1) << 3));
        __hip_atomic_store(dst, v, __ATOMIC_RELAXED, __HIP_MEMORY_SCOPE_AGENT);
      }
    }
    // ---- grid barrier: symmetric all-poll-all, no fences ----
    __syncthreads();                                 // drains all waves' stores
    ++gen;
    if (wv == 0) {
      if (lane == 0)
        __hip_atomic_store(&bar[w], gen, __ATOMIC_RELAXED, __HIP_MEMORY_SCOPE_AGENT);
      for (;;) {
        u64 a = __hip_atomic_load(&arr64[2 * lane],     __ATOMIC_RELAXED, __HIP_MEMORY_SCOPE_AGENT);
        u64 b = __hip_atomic_load(&arr64[2 * lane + 1], __ATOMIC_RELAXED, __HIP_MEMORY_SCOPE_AGENT);
        bool ok = ((unsigned)a >= gen) && ((unsigned)(a >> 32) >= gen)
               && ((unsigned)b >= gen) && ((unsigned)(b >> 32) >= gen);
        if (__all(ok)) break;
        __builtin_amdgcn_s_sleep(2);
      }
    }
    __syncthreads();                                 // release compute waves
  }
}

// ---------------------------------------------------------------------------
// K5: R(t,b,n) = H2[t][b][:] @ dec_VT[n][:] + dec_bVT[n]   (bf16)
// ---------------------------------------------------------------------------
__global__ void __launch_bounds__(256) k_dec1(
    const __hip_bfloat16* __restrict__ H2, const __hip_bfloat16* __restrict__ dec_VTC,
    const float* __restrict__ dbv, __hip_bfloat16* __restrict__ R)
{
  const int t = blockIdx.x;
  const int lane = threadIdx.x & 63, wv = threadIdx.x >> 6;
  const __hip_bfloat16* A = H2 + ((size_t)t << 16) + ((size_t)(wv * 16 + (lane & 15)) << 10);
  const int ko = (lane >> 4) * 8;
  f32x4 acc[4];
  for (int i = 0; i < 4; ++i) acc[i] = fzero();
  for (int ks = 0; ks < 32; ++ks) {
    bf16x8 a = *(const bf16x8*)(A + ks * 32 + ko);
    #pragma unroll
    for (int nt = 0; nt < 4; ++nt) {
      bf16x8 b = *(const bf16x8*)(dec_VTC + ((size_t)(nt * 16 + (lane & 15)) << 10) + ks * 32 + ko);
      acc[nt] = mfma16(a, b, acc[nt]);
    }
  }
  #pragma unroll
  for (int nt = 0; nt < 4; ++nt) {
    int n = nt * 16 + (lane & 15);
    float bias = dbv[n];
    #pragma unroll
    for (int r = 0; r < 4; ++r) {
      int b_row = wv * 16 + (lane >> 4) * 4 + r;
      R[((size_t)t << 12) + (size_t)b_row * 64 + n] = __float2bfloat16(acc[nt][r] + bias);
    }
  }
}

// ---------------------------------------------------------------------------
// K6: out[b][v][t] = R(t,b,:) @ dec_U[v][:] + dec_bU[v]; store dtype = mode
// ---------------------------------------------------------------------------
__global__ void __launch_bounds__(256) k_dec2(
    const __hip_bfloat16* __restrict__ R, const __hip_bfloat16* __restrict__ dec_UC,
    const float* __restrict__ dbu, void* __restrict__ out,
    const int* __restrict__ flags)
{
  const int mode = flags[0];
  const int bblk = blockIdx.x >> 4, tblk = blockIdx.x & 15;
  const int lane = threadIdx.x & 63, wv = threadIdx.x >> 6;
  const int ko  = (lane >> 4) * 8;
  const int t_l = lane & 15;
  for (int bi = 0; bi < 4; ++bi) {
    const int b = bblk * 16 + wv * 4 + bi;
    f32x4 acc[16];
    for (int i = 0; i < 16; ++i) acc[i] = fzero();
    #pragma unroll
    for (int ks = 0; ks < 2; ++ks) {
      bf16x8 a = *(const bf16x8*)(R + (((size_t)(tblk * 16 + t_l) * 64 + b) << 6)
                                    + ks * 32 + ko);
      #pragma unroll
      for (int nt = 0; nt < 16; ++nt) {
        bf16x8 bb = *(const bf16x8*)(dec_UC + ((size_t)(nt * 16 + t_l) << 6) + ks * 32 + ko);
        acc[nt] = mfma16(a, bb, acc[nt]);
      }
    }
    #pragma unroll
    for (int nt = 0; nt < 16; ++nt) {
      int v = nt * 16 + t_l;
      float bias = dbu[v];
      size_t off = (size_t)b * 65536 + (size_t)v * 256 + tblk * 16 + (lane >> 4) * 4;
      if (mode) {
        float4 st;
        st.x = acc[nt][0] + bias; st.y = acc[nt][1] + bias;
        st.z = acc[nt][2] + bias; st.w = acc[nt][3] + bias;
        *(float4*)((float*)out + off) = st;
      } else {
        union { bf16x4 v4; __hip_bfloat16 h[4]; } u;
        #pragma unroll
        for (int r = 0; r < 4; ++r) u.h[r] = __float2bfloat16(acc[nt][r] + bias);
        *(bf16x4*)((__hip_bfloat16*)out + off) = u.v4;
      }
    }
  }
}

// ---------------------------------------------------------------------------
extern "C" void kernel_launch(void* const* d_in, const int* in_sizes, int n_in,
                              void* d_out, int out_size, void* d_ws, size_t ws_size,
                              hipStream_t stream)
{
  const int* tokens  = (const int*)d_in[0];
  const void* embed  = d_in[1];
  const void* VT_ih  = d_in[2];
  const void* bVT_ih = d_in[3];
  const void* U_ih   = d_in[4];
  const void* bU_ih  = d_in[5];
  const void* VT_hh  = d_in[6];
  const void* bVT_hh = d_in[7];
  const void* U_hh   = d_in[8];
  const void* bU_hh  = d_in[9];
  const void* dec_VT = d_in[10];
  const void* dec_bVT= d_in[11];
  const void* dec_U  = d_in[12];
  const void* dec_bU = d_in[13];

  char* ws = (char*)d_ws;
  const size_t M = 1024 * 1024;
  // ws layout (100 MB total in big mode, 68 MB in fallback):
  __hip_bfloat16* Wc      = (__hip_bfloat16*)ws;                    // [0,32MB)
  __hip_bfloat16* H2      = (__hip_bfloat16*)(ws + 32 * M);         // [32,64MB)
  char* aux = ws + 64 * M;                                          // [64,68MB)
  int*            flags   = (int*)aux;                              // 256B
  float*          bc      = (float*)(aux + 4096);                   // 32KB
  float*          dbv     = (float*)(aux + 36864);                  // 256B
  float*          dbu     = (float*)(aux + 37120);                  // 1KB
  __hip_bfloat16* embedC  = (__hip_bfloat16*)(aux + 65536);         // 512KB
  __hip_bfloat16* dec_VTC = (__hip_bfloat16*)(aux + 589824);        // 128KB
  __hip_bfloat16* dec_UC  = (__hip_bfloat16*)(aux + 720896);        // 32KB
  __hip_bfloat16* H1ring  = (__hip_bfloat16*)(aux + 1048576);       // 512KB
  unsigned*       bar     = (unsigned*)(aux + 1572864);             // 1KB (256 slots)
  __hip_bfloat16* R       = (__hip_bfloat16*)(aux + 2097152);       // 2MB
  __hip_bfloat16* H1big   = (__hip_bfloat16*)(ws + 68 * M);         // [68,100MB)

  (void)in_sizes; (void)n_in; (void)out_size;

  // big mode: t-unique H1 (fresh addresses) -> all H reads L2-cached
  const int big = (ws_size >= (size_t)100 * M);
  __hip_bfloat16* H1 = big ? H1big : H1ring;
  const int h1mask = big ? 255 : 3;
  const int cmode  = big ? 1 : 0;

  hipFuncSetAttribute((const void*)k_lstm,
                      hipFuncAttributeMaxDynamicSharedMemorySize, 140288);

  k_detect<<<1, 256, 0, stream>>>((const unsigned short*)embed, flags);
  k_cvt_b<<<256, 256, 0, stream>>>(embed,  embedC,  256 * 1024, flags);
  k_cvt_b<<<64,  256, 0, stream>>>(dec_VT, dec_VTC, 64 * 1024,  flags);
  k_cvt_b<<<16,  256, 0, stream>>>(dec_U,  dec_UC,  256 * 64,   flags);
  k_cvt_f<<<1,   64,  0, stream>>>(dec_bVT, dbv, 64,  flags);
  k_cvt_f<<<1,   256, 0, stream>>>(dec_bU,  dbu, 256, flags);
  k_combine<<<4096, 256, 0, stream>>>(U_ih, U_hh, VT_ih, VT_hh, Wc, flags);
  k_bias   <<<2048, 256, 0, stream>>>(bVT_ih, U_ih, bU_ih, bVT_hh, U_hh, bU_hh, bc, flags);
  k_init   <<<1, 256, 0, stream>>>(bar);
  k_lstm   <<<256, 256, 140288, stream>>>(tokens, embedC, Wc, bc, H1, H2, bar,
                                          h1mask, cmode);
  k_dec1   <<<256, 256, 0, stream>>>(H2, dec_VTC, dbv, R);
  k_dec2   <<<64, 256, 0, stream>>>(R, dec_UC, dbu, d_out, flags);
}

// Round 2
// 4441.822 us; speedup vs baseline: 1.4112x; 1.0549x over previous
//
#include <hip/hip_runtime.h>
#include <hip/hip_bf16.h>

// LowRankNextCharacterLSTM on MI355X (gfx950). Inputs fp32 (runtime-detected,
// canonicalized to bf16); output fp32 (mode-matched store).
//
// Algebra: R_GATE == HIDDEN -> fold W = U@VT ([4096,1024]),
// b = bU_ih + bU_hh + bVT_ih@U_ih^T + bVT_hh@U_hh^T; then
//   gates = x @ W_ih^T + h @ W_hh^T + b.
// Recurrence: ONE persistent kernel, 256 WGs (1 block/CU via 137KB LDS),
// weights staged to LDS once, two layers pipelined, 257 grid barriers.
//
// Round 10: register-prefetch the whole A strip in the cached GEMM path.
// Round-9 counters showed VGPR_Count=48 -> only ~5 of the 64 A-loads in
// flight -> ~13 serial LLC round-trips per step (fresh t-unique lines always
// miss the local L2 first). LDS caps us at 1 WG/CU = 1 wave/SIMD, so the
// per-wave VGPR budget is 512; we now use ~300: p0[32]+p1[32] bf16x8
// register arrays, fully unrolled static indexing, all 64 16B loads issued
// back-to-back from one base pointer + immediate offsets (<2KB, fits the
// 13-bit imm). Collapses the load-latency chain to ~1 round trip.
//
// Coherence by address freshness (round 9, unchanged):
//   - every H tile is written to a t-unique address (H2 [t]; H1 [256] when
//     ws_size >= 100MB, else legacy 4-deep ring + bypass-atomic loads),
//   - producers store write-through (sc0 sc1) and drain before the arrival
//     flag, so the LLC holds the data before any reader can miss-fetch it,
//   - a fresh line can therefore never be stale in any XCD's L1/L2.
// Barrier: symmetric all-poll-all on 256 packed arrival slots, no fences.

#define B_SZ   64
#define T_SEQ  256
#define HID    1024
#define G4     4096

typedef __attribute__((ext_vector_type(8))) short bf16x8;
typedef __attribute__((ext_vector_type(4))) float f32x4;
typedef __attribute__((ext_vector_type(4))) short bf16x4;
typedef unsigned long long u64;

__device__ __forceinline__ f32x4 mfma16(bf16x8 a, bf16x8 b, f32x4 c) {
  return __builtin_amdgcn_mfma_f32_16x16x32_bf16(a, b, c, 0, 0, 0);
}
__device__ __forceinline__ float sigm(float x)  { return 1.f / (1.f + __expf(-x)); }
__device__ __forceinline__ float tanh_(float x) { return 2.f / (1.f + __expf(-2.f * x)) - 1.f; }
__device__ __forceinline__ f32x4 fzero() { f32x4 z; z[0]=0.f; z[1]=0.f; z[2]=0.f; z[3]=0.f; return z; }

// L2-bypass (agent-coherent) 16B load as 2x64-bit relaxed atomics
__device__ __forceinline__ bf16x8 lda(const __hip_bfloat16* p) {
  const u64* q = (const u64*)p;
  union { u64 u[2]; bf16x8 v; } r;
  r.u[0] = __hip_atomic_load(q,     __ATOMIC_RELAXED, __HIP_MEMORY_SCOPE_AGENT);
  r.u[1] = __hip_atomic_load(q + 1, __ATOMIC_RELAXED, __HIP_MEMORY_SCOPE_AGENT);
  return r.v;
}

// mode: 1 = inputs stored fp32, 0 = bf16
__device__ __forceinline__ float ld1(const void* p, size_t i, int mode) {
  return mode ? ((const float*)p)[i]
              : __bfloat162float(((const __hip_bfloat16*)p)[i]);
}
__device__ __forceinline__ bf16x8 ld8(const void* p, size_t i, int mode) {
  if (mode) {
    const float* f = (const float*)p + i;
    float4 a = *(const float4*)f;
    float4 b = *(const float4*)(f + 4);
    union { bf16x8 v; __hip_bfloat16 h[8]; } u;
    u.h[0] = __float2bfloat16(a.x); u.h[1] = __float2bfloat16(a.y);
    u.h[2] = __float2bfloat16(a.z); u.h[3] = __float2bfloat16(a.w);
    u.h[4] = __float2bfloat16(b.x); u.h[5] = __float2bfloat16(b.y);
    u.h[6] = __float2bfloat16(b.z); u.h[7] = __float2bfloat16(b.w);
    return u.v;
  }
  return *(const bf16x8*)((const __hip_bfloat16*)p + i);
}

// ---------------------------------------------------------------------------
__global__ void k_detect(const unsigned short* __restrict__ e, int* __restrict__ flags) {
  __shared__ int cnt;
  if (threadIdx.x == 0) cnt = 0;
  __syncthreads();
  int c = 0;
  for (int i = threadIdx.x; i < 2048; i += 256) {
    unsigned int bits = ((unsigned int)e[2 * i]) << 16;
    float f = __uint_as_float(bits);
    if (!isfinite(f) || fabsf(f) > 1e10f) ++c;
  }
  atomicAdd(&cnt, c);
  __syncthreads();
  if (threadIdx.x == 0) flags[0] = (cnt > 8) ? 1 : 0;
}

__global__ void k_cvt_b(const void* __restrict__ src, __hip_bfloat16* __restrict__ dst,
                        int n, const int* __restrict__ flags) {
  const int mode = flags[0];
  for (int i = blockIdx.x * blockDim.x + threadIdx.x; i < n; i += gridDim.x * blockDim.x)
    dst[i] = mode ? __float2bfloat16(((const float*)src)[i])
                  : ((const __hip_bfloat16*)src)[i];
}
__global__ void k_cvt_f(const void* __restrict__ src, float* __restrict__ dst,
                        int n, const int* __restrict__ flags) {
  const int mode = flags[0];
  for (int i = blockIdx.x * blockDim.x + threadIdx.x; i < n; i += gridDim.x * blockDim.x)
    dst[i] = mode ? ((const float*)src)[i]
                  : __bfloat162float(((const __hip_bfloat16*)src)[i]);
}

// zero the 256 packed arrival slots
__global__ void k_init(unsigned* bar) {
  bar[threadIdx.x] = 0u;
}

// ---------------------------------------------------------------------------
// K2: Wc[Mid] = U @ VT  (Mid = L*2+typ; typ 0=ih 1=hh), bf16 out, f32 acc
// ---------------------------------------------------------------------------
__global__ void __launch_bounds__(256) k_combine(
    const void* __restrict__ U_ih, const void* __restrict__ U_hh,
    const void* __restrict__ VT_ih, const void* __restrict__ VT_hh,
    __hip_bfloat16* __restrict__ Wc, const int* __restrict__ flags)
{
  __shared__ __hip_bfloat16 sB[4 * 64 * 8];
  const int mode = flags[0];
  const int idx  = blockIdx.x;
  const int Mid  = idx >> 10;
  const int rem  = idx & 1023;
  const int gblk = rem >> 4, kblk = rem & 15;
  const int L = Mid >> 1, typ = Mid & 1;
  const void* U  = typ ? U_hh  : U_ih;
  const void* VT = typ ? VT_hh : VT_ih;
  const size_t Uoff  = (size_t)L * G4 * HID;
  const size_t VToff = (size_t)L * HID * HID;
  const int tid = threadIdx.x, lane = tid & 63, wv = tid >> 6;

  f32x4 acc[4];
  for (int i = 0; i < 4; ++i) acc[i] = fzero();

  const int r_local = tid >> 3;
  const int kk8     = (tid & 7) * 8;

  for (int r0 = 0; r0 < HID; r0 += 32) {
    union { bf16x8 v; __hip_bfloat16 h[8]; } u;
    u.v = ld8(VT, VToff + (size_t)(r0 + r_local) * HID + kblk * 64 + kk8, mode);
    __syncthreads();
    #pragma unroll
    for (int j = 0; j < 8; ++j) {
      int k_local = kk8 + j;
      int tile = k_local >> 4;
      int ln   = ((r_local >> 3) << 4) | (k_local & 15);
      sB[(tile * 64 + ln) * 8 + (r_local & 7)] = u.h[j];
    }
    __syncthreads();
    bf16x8 a = ld8(U, Uoff + (size_t)(gblk * 64 + wv * 16 + (lane & 15)) * HID
                          + r0 + (lane >> 4) * 8, mode);
    #pragma unroll
    for (int nt = 0; nt < 4; ++nt) {
      bf16x8 b = *(const bf16x8*)(sB + (nt * 64 + lane) * 8);
      acc[nt] = mfma16(a, b, acc[nt]);
    }
  }
  #pragma unroll
  for (int nt = 0; nt < 4; ++nt)
    #pragma unroll
    for (int r = 0; r < 4; ++r) {
      int g = gblk * 64 + wv * 16 + (lane >> 4) * 4 + r;
      int k = kblk * 64 + nt * 16 + (lane & 15);
      Wc[((size_t)Mid * G4 + g) * HID + k] = __float2bfloat16(acc[nt][r]);
    }
}

// ---------------------------------------------------------------------------
// K3: bc[L][g] = bU_ih + bU_hh + bVT_ih@U_ih^T + bVT_hh@U_hh^T   (f32)
// ---------------------------------------------------------------------------
__global__ void __launch_bounds__(256) k_bias(
    const void* __restrict__ bVT_ih, const void* __restrict__ U_ih,
    const void* __restrict__ bU_ih,
    const void* __restrict__ bVT_hh, const void* __restrict__ U_hh,
    const void* __restrict__ bU_hh,
    float* __restrict__ bc, const int* __restrict__ flags)
{
  const int mode  = flags[0];
  const int g_all = blockIdx.x * 4 + (threadIdx.x >> 6);
  const int lane  = threadIdx.x & 63;
  const int L = g_all >> 12, g = g_all & 4095;
  const size_t ub = (size_t)(L * G4 + g) * HID + lane * 16;
  const size_t vb = (size_t)L * HID + lane * 16;
  float s = 0.f;
  #pragma unroll
  for (int c = 0; c < 16; ++c)
    s += ld1(bVT_ih, vb + c, mode) * ld1(U_ih, ub + c, mode)
       + ld1(bVT_hh, vb + c, mode) * ld1(U_hh, ub + c, mode);
  for (int off = 32; off; off >>= 1) s += __shfl_down(s, off);
  if (lane == 0)
    bc[g_all] = s + ld1(bU_ih, L * G4 + g, mode) + ld1(bU_hh, L * G4 + g, mode);
}

// ---------------------------------------------------------------------------
// K4: persistent pipelined LSTM. 256 WGs; WG w: L=w>>7, jg=w&127 (h cols
// [8jg,8jg+8)). Weights in LDS once (B-frag order). waves 0,1 = x-path,
// waves 2,3 = h-path. Macro-step s: L0 does t=s, L1 does t=s-1.
// cmode=1: H1/H2 reads are plain L2-cached loads (t-unique addresses keep
// them coherent). cmode=0: legacy bypass-atomic reads of the 4-deep H1 ring.
// ---------------------------------------------------------------------------
__global__ void __launch_bounds__(256, 1) k_lstm(
    const int* __restrict__ tokens, const __hip_bfloat16* __restrict__ embedC,
    const __hip_bfloat16* __restrict__ Wc, const float* __restrict__ bc,
    __hip_bfloat16* __restrict__ H1, __hip_bfloat16* __restrict__ H2,
    unsigned* bar, const int h1mask, const int cmode)
{
  extern __shared__ char smem[];
  __hip_bfloat16* Wl = (__hip_bfloat16*)smem;            // 128KB, B-frag order
  f32x4* Xex = (f32x4*)(smem + 131072);                  // 8KB exchange
  __hip_bfloat16* Hs = (__hip_bfloat16*)(smem + 139264); // 1KB h staging [64][8]

  const int tid  = threadIdx.x;
  const int lane = tid & 63, wv = tid >> 6;
  const int w    = blockIdx.x;
  const int L    = w >> 7, jg = w & 127;
  const int mat  = wv >> 1, mhalf = wv & 1;         // 0 = x-path, 1 = h-path
  const u64* arr64 = (const u64*)bar;

  // stage weight slices into LDS once; slot q = [mat(1)][ks(5)][tile(1)][ln(6)]
  for (int q = tid; q < 8192; q += 256) {
    int m_ = q >> 12, ks = (q >> 7) & 31, tl = (q >> 6) & 1, ln = q & 63;
    int n_local = tl * 16 + (ln & 15);
    int g = (n_local >> 3) * 1024 + jg * 8 + (n_local & 7);
    int k = ks * 32 + (ln >> 4) * 8;
    *(bf16x8*)(Wl + (size_t)q * 8) =
        *(const bf16x8*)(Wc + (((size_t)(L * 2 + m_) * G4 + g) << 10) + k);
  }
  const int nb = lane & 7;
  const float b_i = bc[L * G4 +        jg * 8 + nb];
  const float b_f = bc[L * G4 + 1024 + jg * 8 + nb];
  const float b_g = bc[L * G4 + 2048 + jg * 8 + nb];
  const float b_o = bc[L * G4 + 3072 + jg * 8 + nb];
  __syncthreads();

  float cst[2][4] = {{0.f,0.f,0.f,0.f},{0.f,0.f,0.f,0.f}};
  const int m0 = mhalf * 32 + (lane & 15);
  const int ko = (lane >> 4) * 8;
  const __hip_bfloat16* wbase = Wl + mat * 32768;
  unsigned gen = 0;

  for (int s = 0; s <= T_SEQ; ++s) {
    const int t = s - L;
    const bool act = (t >= 0 && t < T_SEQ);          // block-uniform
    if (act) {
      f32x4 acc00 = fzero(), acc01 = fzero(), acc10 = fzero(), acc11 = fzero();
      bool doGemm = true, cached = false;
      const __hip_bfloat16 *A0 = nullptr, *A1 = nullptr;
      if (mat == 0) {
        if (L == 0) {                                // embed: read-only, cached
          A0 = embedC + ((size_t)tokens[m0 * T_SEQ + t] << 10);
          A1 = embedC + ((size_t)tokens[(m0 + 16) * T_SEQ + t] << 10);
          cached = true;
        } else {                                     // H1[t]: fresh address
          A0 = H1 + ((((size_t)(t & h1mask)) * 64 + m0) << 10);
          A1 = A0 + ((size_t)16 << 10);
          cached = (cmode != 0);
        }
      } else {
        if (t == 0) doGemm = false;                  // h_{-1} = 0
        else {
          if (L == 0) {                              // H1[t-1]: fresh address
            A0 = H1 + ((((size_t)((t - 1) & h1mask)) * 64 + m0) << 10);
            cached = (cmode != 0);
          } else {                                   // H2[t-1]: always t-unique
            A0 = H2 + (((size_t)(t - 1) * 64 + m0) << 10);
            cached = true;
          }
          A1 = A0 + ((size_t)16 << 10);
        }
      }
      if (doGemm) {
        if (cached) {
          // Register-prefetch the full A strip: 64 x 16B loads in flight,
          // one base VGPR pair + immediate offsets (max 0x7f0 < 4KB imm).
          // 1 WG/CU -> 1 wave/SIMD -> 512-VGPR budget; ~300 used, no spill.
          bf16x8 p0[32], p1[32];
          #pragma unroll
          for (int i = 0; i < 32; ++i) {
            p0[i] = *(const bf16x8*)(A0 + i * 32 + ko);
            p1[i] = *(const bf16x8*)(A1 + i * 32 + ko);
          }
          #pragma unroll
          for (int ks = 0; ks < 32; ++ks) {
            bf16x8 b0 = *(const bf16x8*)(wbase + (ks * 2 + 0) * 512 + lane * 8);
            bf16x8 b1 = *(const bf16x8*)(wbase + (ks * 2 + 1) * 512 + lane * 8);
            acc00 = mfma16(p0[ks], b0, acc00);
            acc01 = mfma16(p0[ks], b1, acc01);
            acc10 = mfma16(p1[ks], b0, acc10);
            acc11 = mfma16(p1[ks], b1, acc11);
          }
        } else {
          #pragma unroll 4
          for (int ks = 0; ks < 32; ++ks) {
            bf16x8 a0 = lda(A0 + ks * 32 + ko);
            bf16x8 a1 = lda(A1 + ks * 32 + ko);
            bf16x8 b0 = *(const bf16x8*)(wbase + (ks * 2 + 0) * 512 + lane * 8);
            bf16x8 b1 = *(const bf16x8*)(wbase + (ks * 2 + 1) * 512 + lane * 8);
            acc00 = mfma16(a0, b0, acc00);
            acc01 = mfma16(a0, b1, acc01);
            acc10 = mfma16(a1, b0, acc10);
            acc11 = mfma16(a1, b1, acc11);
          }
        }
      }
      if (mat == 0) {
        Xex[(mhalf * 4 + 0) * 64 + lane] = acc00;
        Xex[(mhalf * 4 + 1) * 64 + lane] = acc01;
        Xex[(mhalf * 4 + 2) * 64 + lane] = acc10;
        Xex[(mhalf * 4 + 3) * 64 + lane] = acc11;
      }
      __syncthreads();
      if (mat == 1) {                                // gates -> c,h -> LDS tile
        #pragma unroll
        for (int mt = 0; mt < 2; ++mt) {
          f32x4 aT0 = mt ? acc10 : acc00;
          f32x4 aT1 = mt ? acc11 : acc01;
          f32x4 gx0 = Xex[(mhalf * 4 + mt * 2 + 0) * 64 + lane];
          f32x4 gx1 = Xex[(mhalf * 4 + mt * 2 + 1) * 64 + lane];
          #pragma unroll
          for (int r = 0; r < 4; ++r) {
            float v0 = aT0[r] + gx0[r];
            float v1 = aT1[r] + gx1[r];
            float p0 = __shfl_xor(v0, 8);
            float p1 = __shfl_xor(v1, 8);
            if ((lane & 15) < 8) {
              float iv = sigm(v0 + b_i);
              float fv = sigm(p0 + b_f);
              float gv = tanh_(v1 + b_g);
              float ov = sigm(p1 + b_o);
              float c  = fv * cst[mt][r] + iv * gv;
              cst[mt][r] = c;
              float h  = ov * tanh_(c);
              int m = mhalf * 32 + mt * 16 + (lane >> 4) * 4 + r;
              Hs[m * 8 + (lane & 15)] = __float2bfloat16(h);
            }
          }
        }
      }
      __syncthreads();                               // Hs tile complete
      // flush Hs -> global as 8B agent-coherent (write-through) stores
      if (tid < 128) {
        char* HoutB = (L == 0) ? (char*)(H1 + (((size_t)(t & h1mask)) << 16))
                               : (char*)(H2 + (((size_t)t) << 16));
        u64 v = ((const u64*)Hs)[tid];
        u64* dst = (u64*)(HoutB + ((size_t)(tid >> 1) << 11) + (jg << 4) + ((tid & 1) << 3));
        __hip_atomic_store(dst, v, __ATOMIC_RELAXED, __HIP_MEMORY_SCOPE_AGENT);
      }
    }
    // ---- grid barrier: symmetric all-poll-all, no fences ----
    __syncthreads();                                 // drains all waves' stores
    ++gen;
    if (wv == 0) {
      if (lane == 0)
        __hip_atomic_store(&bar[w], gen, __ATOMIC_RELAXED, __HIP_MEMORY_SCOPE_AGENT);
      for (;;) {
        u64 a = __hip_atomic_load(&arr64[2 * lane],     __ATOMIC_RELAXED, __HIP_MEMORY_SCOPE_AGENT);
        u64 b = __hip_atomic_load(&arr64[2 * lane + 1], __ATOMIC_RELAXED, __HIP_MEMORY_SCOPE_AGENT);
        bool ok = ((unsigned)a >= gen) && ((unsigned)(a >> 32) >= gen)
               && ((unsigned)b >= gen) && ((unsigned)(b >> 32) >= gen);
        if (__all(ok)) break;
        __builtin_amdgcn_s_sleep(2);
      }
    }
    __syncthreads();                                 // release compute waves
  }
}

// ---------------------------------------------------------------------------
// K5: R(t,b,n) = H2[t][b][:] @ dec_VT[n][:] + dec_bVT[n]   (bf16)
// ---------------------------------------------------------------------------
__global__ void __launch_bounds__(256) k_dec1(
    const __hip_bfloat16* __restrict__ H2, const __hip_bfloat16* __restrict__ dec_VTC,
    const float* __restrict__ dbv, __hip_bfloat16* __restrict__ R)
{
  const int t = blockIdx.x;
  const int lane = threadIdx.x & 63, wv = threadIdx.x >> 6;
  const __hip_bfloat16* A = H2 + ((size_t)t << 16) + ((size_t)(wv * 16 + (lane & 15)) << 10);
  const int ko = (lane >> 4) * 8;
  f32x4 acc[4];
  for (int i = 0; i < 4; ++i) acc[i] = fzero();
  for (int ks = 0; ks < 32; ++ks) {
    bf16x8 a = *(const bf16x8*)(A + ks * 32 + ko);
    #pragma unroll
    for (int nt = 0; nt < 4; ++nt) {
      bf16x8 b = *(const bf16x8*)(dec_VTC + ((size_t)(nt * 16 + (lane & 15)) << 10) + ks * 32 + ko);
      acc[nt] = mfma16(a, b, acc[nt]);
    }
  }
  #pragma unroll
  for (int nt = 0; nt < 4; ++nt) {
    int n = nt * 16 + (lane & 15);
    float bias = dbv[n];
    #pragma unroll
    for (int r = 0; r < 4; ++r) {
      int b_row = wv * 16 + (lane >> 4) * 4 + r;
      R[((size_t)t << 12) + (size_t)b_row * 64 + n] = __float2bfloat16(acc[nt][r] + bias);
    }
  }
}

// ---------------------------------------------------------------------------
// K6: out[b][v][t] = R(t,b,:) @ dec_U[v][:] + dec_bU[v]; store dtype = mode
// ---------------------------------------------------------------------------
__global__ void __launch_bounds__(256) k_dec2(
    const __hip_bfloat16* __restrict__ R, const __hip_bfloat16* __restrict__ dec_UC,
    const float* __restrict__ dbu, void* __restrict__ out,
    const int* __restrict__ flags)
{
  const int mode = flags[0];
  const int bblk = blockIdx.x >> 4, tblk = blockIdx.x & 15;
  const int lane = threadIdx.x & 63, wv = threadIdx.x >> 6;
  const int ko  = (lane >> 4) * 8;
  const int t_l = lane & 15;
  for (int bi = 0; bi < 4; ++bi) {
    const int b = bblk * 16 + wv * 4 + bi;
    f32x4 acc[16];
    for (int i = 0; i < 16; ++i) acc[i] = fzero();
    #pragma unroll
    for (int ks = 0; ks < 2; ++ks) {
      bf16x8 a = *(const bf16x8*)(R + (((size_t)(tblk * 16 + t_l) * 64 + b) << 6)
                                    + ks * 32 + ko);
      #pragma unroll
      for (int nt = 0; nt < 16; ++nt) {
        bf16x8 bb = *(const bf16x8*)(dec_UC + ((size_t)(nt * 16 + t_l) << 6) + ks * 32 + ko);
        acc[nt] = mfma16(a, bb, acc[nt]);
      }
    }
    #pragma unroll
    for (int nt = 0; nt < 16; ++nt) {
      int v = nt * 16 + t_l;
      float bias = dbu[v];
      size_t off = (size_t)b * 65536 + (size_t)v * 256 + tblk * 16 + (lane >> 4) * 4;
      if (mode) {
        float4 st;
        st.x = acc[nt][0] + bias; st.y = acc[nt][1] + bias;
        st.z = acc[nt][2] + bias; st.w = acc[nt][3] + bias;
        *(float4*)((float*)out + off) = st;
      } else {
        union { bf16x4 v4; __hip_bfloat16 h[4]; } u;
        #pragma unroll
        for (int r = 0; r < 4; ++r) u.h[r] = __float2bfloat16(acc[nt][r] + bias);
        *(bf16x4*)((__hip_bfloat16*)out + off) = u.v4;
      }
    }
  }
}

// ---------------------------------------------------------------------------
extern "C" void kernel_launch(void* const* d_in, const int* in_sizes, int n_in,
                              void* d_out, int out_size, void* d_ws, size_t ws_size,
                              hipStream_t stream)
{
  const int* tokens  = (const int*)d_in[0];
  const void* embed  = d_in[1];
  const void* VT_ih  = d_in[2];
  const void* bVT_ih = d_in[3];
  const void* U_ih   = d_in[4];
  const void* bU_ih  = d_in[5];
  const void* VT_hh  = d_in[6];
  const void* bVT_hh = d_in[7];
  const void* U_hh   = d_in[8];
  const void* bU_hh  = d_in[9];
  const void* dec_VT = d_in[10];
  const void* dec_bVT= d_in[11];
  const void* dec_U  = d_in[12];
  const void* dec_bU = d_in[13];

  char* ws = (char*)d_ws;
  const size_t M = 1024 * 1024;
  // ws layout (100 MB total in big mode, 68 MB in fallback):
  __hip_bfloat16* Wc      = (__hip_bfloat16*)ws;                    // [0,32MB)
  __hip_bfloat16* H2      = (__hip_bfloat16*)(ws + 32 * M);         // [32,64MB)
  char* aux = ws + 64 * M;                                          // [64,68MB)
  int*            flags   = (int*)aux;                              // 256B
  float*          bc      = (float*)(aux + 4096);                   // 32KB
  float*          dbv     = (float*)(aux + 36864);                  // 256B
  float*          dbu     = (float*)(aux + 37120);                  // 1KB
  __hip_bfloat16* embedC  = (__hip_bfloat16*)(aux + 65536);         // 512KB
  __hip_bfloat16* dec_VTC = (__hip_bfloat16*)(aux + 589824);        // 128KB
  __hip_bfloat16* dec_UC  = (__hip_bfloat16*)(aux + 720896);        // 32KB
  __hip_bfloat16* H1ring  = (__hip_bfloat16*)(aux + 1048576);       // 512KB
  unsigned*       bar     = (unsigned*)(aux + 1572864);             // 1KB (256 slots)
  __hip_bfloat16* R       = (__hip_bfloat16*)(aux + 2097152);       // 2MB
  __hip_bfloat16* H1big   = (__hip_bfloat16*)(ws + 68 * M);         // [68,100MB)

  (void)in_sizes; (void)n_in; (void)out_size;

  // big mode: t-unique H1 (fresh addresses) -> all H reads L2-cached
  const int big = (ws_size >= (size_t)100 * M);
  __hip_bfloat16* H1 = big ? H1big : H1ring;
  const int h1mask = big ? 255 : 3;
  const int cmode  = big ? 1 : 0;

  hipFuncSetAttribute((const void*)k_lstm,
                      hipFuncAttributeMaxDynamicSharedMemorySize, 140288);

  k_detect<<<1, 256, 0, stream>>>((const unsigned short*)embed, flags);
  k_cvt_b<<<256, 256, 0, stream>>>(embed,  embedC,  256 * 1024, flags);
  k_cvt_b<<<64,  256, 0, stream>>>(dec_VT, dec_VTC, 64 * 1024,  flags);
  k_cvt_b<<<16,  256, 0, stream>>>(dec_U,  dec_UC,  256 * 64,   flags);
  k_cvt_f<<<1,   64,  0, stream>>>(dec_bVT, dbv, 64,  flags);
  k_cvt_f<<<1,   256, 0, stream>>>(dec_bU,  dbu, 256, flags);
  k_combine<<<4096, 256, 0, stream>>>(U_ih, U_hh, VT_ih, VT_hh, Wc, flags);
  k_bias   <<<2048, 256, 0, stream>>>(bVT_ih, U_ih, bU_ih, bVT_hh, U_hh, bU_hh, bc, flags);
  k_init   <<<1, 256, 0, stream>>>(bar);
  k_lstm   <<<256, 256, 140288, stream>>>(tokens, embedC, Wc, bc, H1, H2, bar,
                                          h1mask, cmode);
  k_dec1   <<<256, 256, 0, stream>>>(H2, dec_VTC, dbv, R);
  k_dec2   <<<64, 256, 0, stream>>>(R, dec_UC, dbu, d_out, flags);
}

// Round 4
// 4058.251 us; speedup vs baseline: 1.5446x; 1.0945x over previous
//
#include <hip/hip_runtime.h>
#include <hip/hip_bf16.h>

// LowRankNextCharacterLSTM on MI355X (gfx950). Inputs fp32 (runtime-detected,
// canonicalized to bf16); output fp32 (mode-matched store).
//
// Algebra: R_GATE == HIDDEN -> fold W = U@VT ([4096,1024]),
// b = bU_ih + bU_hh + bVT_ih@U_ih^T + bVT_hh@U_hh^T; then
//   gates = x @ W_ih^T + h @ W_hh^T + b.
// Recurrence: ONE persistent kernel, 256 WGs (1 block/CU via 137KB LDS),
// weights staged to LDS once, two layers pipelined, 257 grid barriers.
//
// Round 12 = round 11 resubmitted verbatim (round-11 bench died to an infra
// "container failed twice" with no kernel-attributable evidence; the kernel
// is semantically identical to the passing round-10 one, sched_barrier being
// a pure scheduling directive).
//
// Round 11: round-10's register-prefetch (p0[32]/p1[32]) was silently undone
// by the pre-RA scheduler: VGPR_Count came back 44 (!), i.e. the loads were
// re-interleaved load->use->load->use with ~5 in flight, leaving ~13 serial
// LLC round-trips per step (~9us of the 15.9us step). Fix: pin the schedule
// with __builtin_amdgcn_sched_barrier(0) between the 64-load block and the
// MFMA block. Nothing may cross the barrier -> all 64 loads stay issued
// before any consumer -> regalloc must keep them live (~300 VGPR; we have a
// 512-VGPR budget at 1 wave/SIMD, pinned there by 137KB LDS anyway) -> the
// compiler emits counted vmcnt(N) per consumer = deep load pipeline.
// Validation signal: VGPR_Count must jump to >=260.
//
// Coherence by address freshness (round 9, unchanged):
//   - every H tile is written to a t-unique address (H2 [t]; H1 [256] when
//     ws_size >= 100MB, else legacy 4-deep ring + bypass-atomic loads),
//   - producers store write-through (sc0 sc1) and drain before the arrival
//     flag, so the LLC holds the data before any reader can miss-fetch it,
//   - a fresh line can therefore never be stale in any XCD's L1/L2.
// Barrier: symmetric all-poll-all on 256 packed arrival slots, no fences.

#define B_SZ   64
#define T_SEQ  256
#define HID    1024
#define G4     4096

typedef __attribute__((ext_vector_type(8))) short bf16x8;
typedef __attribute__((ext_vector_type(4))) float f32x4;
typedef __attribute__((ext_vector_type(4))) short bf16x4;
typedef unsigned long long u64;

__device__ __forceinline__ f32x4 mfma16(bf16x8 a, bf16x8 b, f32x4 c) {
  return __builtin_amdgcn_mfma_f32_16x16x32_bf16(a, b, c, 0, 0, 0);
}
__device__ __forceinline__ float sigm(float x)  { return 1.f / (1.f + __expf(-x)); }
__device__ __forceinline__ float tanh_(float x) { return 2.f / (1.f + __expf(-2.f * x)) - 1.f; }
__device__ __forceinline__ f32x4 fzero() { f32x4 z; z[0]=0.f; z[1]=0.f; z[2]=0.f; z[3]=0.f; return z; }

// L2-bypass (agent-coherent) 16B load as 2x64-bit relaxed atomics
__device__ __forceinline__ bf16x8 lda(const __hip_bfloat16* p) {
  const u64* q = (const u64*)p;
  union { u64 u[2]; bf16x8 v; } r;
  r.u[0] = __hip_atomic_load(q,     __ATOMIC_RELAXED, __HIP_MEMORY_SCOPE_AGENT);
  r.u[1] = __hip_atomic_load(q + 1, __ATOMIC_RELAXED, __HIP_MEMORY_SCOPE_AGENT);
  return r.v;
}

// mode: 1 = inputs stored fp32, 0 = bf16
__device__ __forceinline__ float ld1(const void* p, size_t i, int mode) {
  return mode ? ((const float*)p)[i]
              : __bfloat162float(((const __hip_bfloat16*)p)[i]);
}
__device__ __forceinline__ bf16x8 ld8(const void* p, size_t i, int mode) {
  if (mode) {
    const float* f = (const float*)p + i;
    float4 a = *(const float4*)f;
    float4 b = *(const float4*)(f + 4);
    union { bf16x8 v; __hip_bfloat16 h[8]; } u;
    u.h[0] = __float2bfloat16(a.x); u.h[1] = __float2bfloat16(a.y);
    u.h[2] = __float2bfloat16(a.z); u.h[3] = __float2bfloat16(a.w);
    u.h[4] = __float2bfloat16(b.x); u.h[5] = __float2bfloat16(b.y);
    u.h[6] = __float2bfloat16(b.z); u.h[7] = __float2bfloat16(b.w);
    return u.v;
  }
  return *(const bf16x8*)((const __hip_bfloat16*)p + i);
}

// ---------------------------------------------------------------------------
__global__ void k_detect(const unsigned short* __restrict__ e, int* __restrict__ flags) {
  __shared__ int cnt;
  if (threadIdx.x == 0) cnt = 0;
  __syncthreads();
  int c = 0;
  for (int i = threadIdx.x; i < 2048; i += 256) {
    unsigned int bits = ((unsigned int)e[2 * i]) << 16;
    float f = __uint_as_float(bits);
    if (!isfinite(f) || fabsf(f) > 1e10f) ++c;
  }
  atomicAdd(&cnt, c);
  __syncthreads();
  if (threadIdx.x == 0) flags[0] = (cnt > 8) ? 1 : 0;
}

__global__ void k_cvt_b(const void* __restrict__ src, __hip_bfloat16* __restrict__ dst,
                        int n, const int* __restrict__ flags) {
  const int mode = flags[0];
  for (int i = blockIdx.x * blockDim.x + threadIdx.x; i < n; i += gridDim.x * blockDim.x)
    dst[i] = mode ? __float2bfloat16(((const float*)src)[i])
                  : ((const __hip_bfloat16*)src)[i];
}
__global__ void k_cvt_f(const void* __restrict__ src, float* __restrict__ dst,
                        int n, const int* __restrict__ flags) {
  const int mode = flags[0];
  for (int i = blockIdx.x * blockDim.x + threadIdx.x; i < n; i += gridDim.x * blockDim.x)
    dst[i] = mode ? ((const float*)src)[i]
                  : __bfloat162float(((const __hip_bfloat16*)src)[i]);
}

// zero the 256 packed arrival slots
__global__ void k_init(unsigned* bar) {
  bar[threadIdx.x] = 0u;
}

// ---------------------------------------------------------------------------
// K2: Wc[Mid] = U @ VT  (Mid = L*2+typ; typ 0=ih 1=hh), bf16 out, f32 acc
// ---------------------------------------------------------------------------
__global__ void __launch_bounds__(256) k_combine(
    const void* __restrict__ U_ih, const void* __restrict__ U_hh,
    const void* __restrict__ VT_ih, const void* __restrict__ VT_hh,
    __hip_bfloat16* __restrict__ Wc, const int* __restrict__ flags)
{
  __shared__ __hip_bfloat16 sB[4 * 64 * 8];
  const int mode = flags[0];
  const int idx  = blockIdx.x;
  const int Mid  = idx >> 10;
  const int rem  = idx & 1023;
  const int gblk = rem >> 4, kblk = rem & 15;
  const int L = Mid >> 1, typ = Mid & 1;
  const void* U  = typ ? U_hh  : U_ih;
  const void* VT = typ ? VT_hh : VT_ih;
  const size_t Uoff  = (size_t)L * G4 * HID;
  const size_t VToff = (size_t)L * HID * HID;
  const int tid = threadIdx.x, lane = tid & 63, wv = tid >> 6;

  f32x4 acc[4];
  for (int i = 0; i < 4; ++i) acc[i] = fzero();

  const int r_local = tid >> 3;
  const int kk8     = (tid & 7) * 8;

  for (int r0 = 0; r0 < HID; r0 += 32) {
    union { bf16x8 v; __hip_bfloat16 h[8]; } u;
    u.v = ld8(VT, VToff + (size_t)(r0 + r_local) * HID + kblk * 64 + kk8, mode);
    __syncthreads();
    #pragma unroll
    for (int j = 0; j < 8; ++j) {
      int k_local = kk8 + j;
      int tile = k_local >> 4;
      int ln   = ((r_local >> 3) << 4) | (k_local & 15);
      sB[(tile * 64 + ln) * 8 + (r_local & 7)] = u.h[j];
    }
    __syncthreads();
    bf16x8 a = ld8(U, Uoff + (size_t)(gblk * 64 + wv * 16 + (lane & 15)) * HID
                          + r0 + (lane >> 4) * 8, mode);
    #pragma unroll
    for (int nt = 0; nt < 4; ++nt) {
      bf16x8 b = *(const bf16x8*)(sB + (nt * 64 + lane) * 8);
      acc[nt] = mfma16(a, b, acc[nt]);
    }
  }
  #pragma unroll
  for (int nt = 0; nt < 4; ++nt)
    #pragma unroll
    for (int r = 0; r < 4; ++r) {
      int g = gblk * 64 + wv * 16 + (lane >> 4) * 4 + r;
      int k = kblk * 64 + nt * 16 + (lane & 15);
      Wc[((size_t)Mid * G4 + g) * HID + k] = __float2bfloat16(acc[nt][r]);
    }
}

// ---------------------------------------------------------------------------
// K3: bc[L][g] = bU_ih + bU_hh + bVT_ih@U_ih^T + bVT_hh@U_hh^T   (f32)
// ---------------------------------------------------------------------------
__global__ void __launch_bounds__(256) k_bias(
    const void* __restrict__ bVT_ih, const void* __restrict__ U_ih,
    const void* __restrict__ bU_ih,
    const void* __restrict__ bVT_hh, const void* __restrict__ U_hh,
    const void* __restrict__ bU_hh,
    float* __restrict__ bc, const int* __restrict__ flags)
{
  const int mode  = flags[0];
  const int g_all = blockIdx.x * 4 + (threadIdx.x >> 6);
  const int lane  = threadIdx.x & 63;
  const int L = g_all >> 12, g = g_all & 4095;
  const size_t ub = (size_t)(L * G4 + g) * HID + lane * 16;
  const size_t vb = (size_t)L * HID + lane * 16;
  float s = 0.f;
  #pragma unroll
  for (int c = 0; c < 16; ++c)
    s += ld1(bVT_ih, vb + c, mode) * ld1(U_ih, ub + c, mode)
       + ld1(bVT_hh, vb + c, mode) * ld1(U_hh, ub + c, mode);
  for (int off = 32; off; off >>= 1) s += __shfl_down(s, off);
  if (lane == 0)
    bc[g_all] = s + ld1(bU_ih, L * G4 + g, mode) + ld1(bU_hh, L * G4 + g, mode);
}

// ---------------------------------------------------------------------------
// K4: persistent pipelined LSTM. 256 WGs; WG w: L=w>>7, jg=w&127 (h cols
// [8jg,8jg+8)). Weights in LDS once (B-frag order). waves 0,1 = x-path,
// waves 2,3 = h-path. Macro-step s: L0 does t=s, L1 does t=s-1.
// cmode=1: H1/H2 reads are plain L2-cached loads (t-unique addresses keep
// them coherent). cmode=0: legacy bypass-atomic reads of the 4-deep H1 ring.
// ---------------------------------------------------------------------------
__global__ void __launch_bounds__(256, 1) k_lstm(
    const int* __restrict__ tokens, const __hip_bfloat16* __restrict__ embedC,
    const __hip_bfloat16* __restrict__ Wc, const float* __restrict__ bc,
    __hip_bfloat16* __restrict__ H1, __hip_bfloat16* __restrict__ H2,
    unsigned* bar, const int h1mask, const int cmode)
{
  extern __shared__ char smem[];
  __hip_bfloat16* Wl = (__hip_bfloat16*)smem;            // 128KB, B-frag order
  f32x4* Xex = (f32x4*)(smem + 131072);                  // 8KB exchange
  __hip_bfloat16* Hs = (__hip_bfloat16*)(smem + 139264); // 1KB h staging [64][8]

  const int tid  = threadIdx.x;
  const int lane = tid & 63, wv = tid >> 6;
  const int w    = blockIdx.x;
  const int L    = w >> 7, jg = w & 127;
  const int mat  = wv >> 1, mhalf = wv & 1;         // 0 = x-path, 1 = h-path
  const u64* arr64 = (const u64*)bar;

  // stage weight slices into LDS once; slot q = [mat(1)][ks(5)][tile(1)][ln(6)]
  for (int q = tid; q < 8192; q += 256) {
    int m_ = q >> 12, ks = (q >> 7) & 31, tl = (q >> 6) & 1, ln = q & 63;
    int n_local = tl * 16 + (ln & 15);
    int g = (n_local >> 3) * 1024 + jg * 8 + (n_local & 7);
    int k = ks * 32 + (ln >> 4) * 8;
    *(bf16x8*)(Wl + (size_t)q * 8) =
        *(const bf16x8*)(Wc + (((size_t)(L * 2 + m_) * G4 + g) << 10) + k);
  }
  const int nb = lane & 7;
  const float b_i = bc[L * G4 +        jg * 8 + nb];
  const float b_f = bc[L * G4 + 1024 + jg * 8 + nb];
  const float b_g = bc[L * G4 + 2048 + jg * 8 + nb];
  const float b_o = bc[L * G4 + 3072 + jg * 8 + nb];
  __syncthreads();

  float cst[2][4] = {{0.f,0.f,0.f,0.f},{0.f,0.f,0.f,0.f}};
  const int m0 = mhalf * 32 + (lane & 15);
  const int ko = (lane >> 4) * 8;
  const __hip_bfloat16* wbase = Wl + mat * 32768;
  unsigned gen = 0;

  for (int s = 0; s <= T_SEQ; ++s) {
    const int t = s - L;
    const bool act = (t >= 0 && t < T_SEQ);          // block-uniform
    if (act) {
      f32x4 acc00 = fzero(), acc01 = fzero(), acc10 = fzero(), acc11 = fzero();
      bool doGemm = true, cached = false;
      const __hip_bfloat16 *A0 = nullptr, *A1 = nullptr;
      if (mat == 0) {
        if (L == 0) {                                // embed: read-only, cached
          A0 = embedC + ((size_t)tokens[m0 * T_SEQ + t] << 10);
          A1 = embedC + ((size_t)tokens[(m0 + 16) * T_SEQ + t] << 10);
          cached = true;
        } else {                                     // H1[t]: fresh address
          A0 = H1 + ((((size_t)(t & h1mask)) * 64 + m0) << 10);
          A1 = A0 + ((size_t)16 << 10);
          cached = (cmode != 0);
        }
      } else {
        if (t == 0) doGemm = false;                  // h_{-1} = 0
        else {
          if (L == 0) {                              // H1[t-1]: fresh address
            A0 = H1 + ((((size_t)((t - 1) & h1mask)) * 64 + m0) << 10);
            cached = (cmode != 0);
          } else {                                   // H2[t-1]: always t-unique
            A0 = H2 + (((size_t)(t - 1) * 64 + m0) << 10);
            cached = true;
          }
          A1 = A0 + ((size_t)16 << 10);
        }
      }
      if (doGemm) {
        if (cached) {
          // Register-prefetch the full A strip: 64 x 16B loads issued
          // back-to-back (one base VGPR pair + immediate offsets < 4KB).
          // The sched_barrier(0) pins the schedule: nothing may cross, so
          // all 64 loads stay in flight and regalloc keeps them live
          // (~300 VGPR; budget is 512 at 1 wave/SIMD). Compiler then emits
          // counted vmcnt(N) per consumer = deep pipeline.
          bf16x8 p0[32], p1[32];
          #pragma unroll
          for (int i = 0; i < 32; ++i) {
            p0[i] = *(const bf16x8*)(A0 + i * 32 + ko);
            p1[i] = *(const bf16x8*)(A1 + i * 32 + ko);
          }
          __builtin_amdgcn_sched_barrier(0);
          #pragma unroll
          for (int ks = 0; ks < 32; ++ks) {
            bf16x8 b0 = *(const bf16x8*)(wbase + (ks * 2 + 0) * 512 + lane * 8);
            bf16x8 b1 = *(const bf16x8*)(wbase + (ks * 2 + 1) * 512 + lane * 8);
            acc00 = mfma16(p0[ks], b0, acc00);
            acc01 = mfma16(p0[ks], b1, acc01);
            acc10 = mfma16(p1[ks], b0, acc10);
            acc11 = mfma16(p1[ks], b1, acc11);
          }
        } else {
          #pragma unroll 4
          for (int ks = 0; ks < 32; ++ks) {
            bf16x8 a0 = lda(A0 + ks * 32 + ko);
            bf16x8 a1 = lda(A1 + ks * 32 + ko);
            bf16x8 b0 = *(const bf16x8*)(wbase + (ks * 2 + 0) * 512 + lane * 8);
            bf16x8 b1 = *(const bf16x8*)(wbase + (ks * 2 + 1) * 512 + lane * 8);
            acc00 = mfma16(a0, b0, acc00);
            acc01 = mfma16(a0, b1, acc01);
            acc10 = mfma16(a1, b0, acc10);
            acc11 = mfma16(a1, b1, acc11);
          }
        }
      }
      if (mat == 0) {
        Xex[(mhalf * 4 + 0) * 64 + lane] = acc00;
        Xex[(mhalf * 4 + 1) * 64 + lane] = acc01;
        Xex[(mhalf * 4 + 2) * 64 + lane] = acc10;
        Xex[(mhalf * 4 + 3) * 64 + lane] = acc11;
      }
      __syncthreads();
      if (mat == 1) {                                // gates -> c,h -> LDS tile
        #pragma unroll
        for (int mt = 0; mt < 2; ++mt) {
          f32x4 aT0 = mt ? acc10 : acc00;
          f32x4 aT1 = mt ? acc11 : acc01;
          f32x4 gx0 = Xex[(mhalf * 4 + mt * 2 + 0) * 64 + lane];
          f32x4 gx1 = Xex[(mhalf * 4 + mt * 2 + 1) * 64 + lane];
          #pragma unroll
          for (int r = 0; r < 4; ++r) {
            float v0 = aT0[r] + gx0[r];
            float v1 = aT1[r] + gx1[r];
            float p0 = __shfl_xor(v0, 8);
            float p1 = __shfl_xor(v1, 8);
            if ((lane & 15) < 8) {
              float iv = sigm(v0 + b_i);
              float fv = sigm(p0 + b_f);
              float gv = tanh_(v1 + b_g);
              float ov = sigm(p1 + b_o);
              float c  = fv * cst[mt][r] + iv * gv;
              cst[mt][r] = c;
              float h  = ov * tanh_(c);
              int m = mhalf * 32 + mt * 16 + (lane >> 4) * 4 + r;
              Hs[m * 8 + (lane & 15)] = __float2bfloat16(h);
            }
          }
        }
      }
      __syncthreads();                               // Hs tile complete
      // flush Hs -> global as 8B agent-coherent (write-through) stores
      if (tid < 128) {
        char* HoutB = (L == 0) ? (char*)(H1 + (((size_t)(t & h1mask)) << 16))
                               : (char*)(H2 + (((size_t)t) << 16));
        u64 v = ((const u64*)Hs)[tid];
        u64* dst = (u64*)(HoutB + ((size_t)(tid >> 1) << 11) + (jg << 4) + ((tid & 1) << 3));
        __hip_atomic_store(dst, v, __ATOMIC_RELAXED, __HIP_MEMORY_SCOPE_AGENT);
      }
    }
    // ---- grid barrier: symmetric all-poll-all, no fences ----
    __syncthreads();                                 // drains all waves' stores
    ++gen;
    if (wv == 0) {
      if (lane == 0)
        __hip_atomic_store(&bar[w], gen, __ATOMIC_RELAXED, __HIP_MEMORY_SCOPE_AGENT);
      for (;;) {
        u64 a = __hip_atomic_load(&arr64[2 * lane],     __ATOMIC_RELAXED, __HIP_MEMORY_SCOPE_AGENT);
        u64 b = __hip_atomic_load(&arr64[2 * lane + 1], __ATOMIC_RELAXED, __HIP_MEMORY_SCOPE_AGENT);
        bool ok = ((unsigned)a >= gen) && ((unsigned)(a >> 32) >= gen)
               && ((unsigned)b >= gen) && ((unsigned)(b >> 32) >= gen);
        if (__all(ok)) break;
        __builtin_amdgcn_s_sleep(2);
      }
    }
    __syncthreads();                                 // release compute waves
  }
}

// ---------------------------------------------------------------------------
// K5: R(t,b,n) = H2[t][b][:] @ dec_VT[n][:] + dec_bVT[n]   (bf16)
// ---------------------------------------------------------------------------
__global__ void __launch_bounds__(256) k_dec1(
    const __hip_bfloat16* __restrict__ H2, const __hip_bfloat16* __restrict__ dec_VTC,
    const float* __restrict__ dbv, __hip_bfloat16* __restrict__ R)
{
  const int t = blockIdx.x;
  const int lane = threadIdx.x & 63, wv = threadIdx.x >> 6;
  const __hip_bfloat16* A = H2 + ((size_t)t << 16) + ((size_t)(wv * 16 + (lane & 15)) << 10);
  const int ko = (lane >> 4) * 8;
  f32x4 acc[4];
  for (int i = 0; i < 4; ++i) acc[i] = fzero();
  for (int ks = 0; ks < 32; ++ks) {
    bf16x8 a = *(const bf16x8*)(A + ks * 32 + ko);
    #pragma unroll
    for (int nt = 0; nt < 4; ++nt) {
      bf16x8 b = *(const bf16x8*)(dec_VTC + ((size_t)(nt * 16 + (lane & 15)) << 10) + ks * 32 + ko);
      acc[nt] = mfma16(a, b, acc[nt]);
    }
  }
  #pragma unroll
  for (int nt = 0; nt < 4; ++nt) {
    int n = nt * 16 + (lane & 15);
    float bias = dbv[n];
    #pragma unroll
    for (int r = 0; r < 4; ++r) {
      int b_row = wv * 16 + (lane >> 4) * 4 + r;
      R[((size_t)t << 12) + (size_t)b_row * 64 + n] = __float2bfloat16(acc[nt][r] + bias);
    }
  }
}

// ---------------------------------------------------------------------------
// K6: out[b][v][t] = R(t,b,:) @ dec_U[v][:] + dec_bU[v]; store dtype = mode
// ---------------------------------------------------------------------------
__global__ void __launch_bounds__(256) k_dec2(
    const __hip_bfloat16* __restrict__ R, const __hip_bfloat16* __restrict__ dec_UC,
    const float* __restrict__ dbu, void* __restrict__ out,
    const int* __restrict__ flags)
{
  const int mode = flags[0];
  const int bblk = blockIdx.x >> 4, tblk = blockIdx.x & 15;
  const int lane = threadIdx.x & 63, wv = threadIdx.x >> 6;
  const int ko  = (lane >> 4) * 8;
  const int t_l = lane & 15;
  for (int bi = 0; bi < 4; ++bi) {
    const int b = bblk * 16 + wv * 4 + bi;
    f32x4 acc[16];
    for (int i = 0; i < 16; ++i) acc[i] = fzero();
    #pragma unroll
    for (int ks = 0; ks < 2; ++ks) {
      bf16x8 a = *(const bf16x8*)(R + (((size_t)(tblk * 16 + t_l) * 64 + b) << 6)
                                    + ks * 32 + ko);
      #pragma unroll
      for (int nt = 0; nt < 16; ++nt) {
        bf16x8 bb = *(const bf16x8*)(dec_UC + ((size_t)(nt * 16 + t_l) << 6) + ks * 32 + ko);
        acc[nt] = mfma16(a, bb, acc[nt]);
      }
    }
    #pragma unroll
    for (int nt = 0; nt < 16; ++nt) {
      int v = nt * 16 + t_l;
      float bias = dbu[v];
      size_t off = (size_t)b * 65536 + (size_t)v * 256 + tblk * 16 + (lane >> 4) * 4;
      if (mode) {
        float4 st;
        st.x = acc[nt][0] + bias; st.y = acc[nt][1] + bias;
        st.z = acc[nt][2] + bias; st.w = acc[nt][3] + bias;
        *(float4*)((float*)out + off) = st;
      } else {
        union { bf16x4 v4; __hip_bfloat16 h[4]; } u;
        #pragma unroll
        for (int r = 0; r < 4; ++r) u.h[r] = __float2bfloat16(acc[nt][r] + bias);
        *(bf16x4*)((__hip_bfloat16*)out + off) = u.v4;
      }
    }
  }
}

// ---------------------------------------------------------------------------
extern "C" void kernel_launch(void* const* d_in, const int* in_sizes, int n_in,
                              void* d_out, int out_size, void* d_ws, size_t ws_size,
                              hipStream_t stream)
{
  const int* tokens  = (const int*)d_in[0];
  const void* embed  = d_in[1];
  const void* VT_ih  = d_in[2];
  const void* bVT_ih = d_in[3];
  const void* U_ih   = d_in[4];
  const void* bU_ih  = d_in[5];
  const void* VT_hh  = d_in[6];
  const void* bVT_hh = d_in[7];
  const void* U_hh   = d_in[8];
  const void* bU_hh  = d_in[9];
  const void* dec_VT = d_in[10];
  const void* dec_bVT= d_in[11];
  const void* dec_U  = d_in[12];
  const void* dec_bU = d_in[13];

  char* ws = (char*)d_ws;
  const size_t M = 1024 * 1024;
  // ws layout (100 MB total in big mode, 68 MB in fallback):
  __hip_bfloat16* Wc      = (__hip_bfloat16*)ws;                    // [0,32MB)
  __hip_bfloat16* H2      = (__hip_bfloat16*)(ws + 32 * M);         // [32,64MB)
  char* aux = ws + 64 * M;                                          // [64,68MB)
  int*            flags   = (int*)aux;                              // 256B
  float*          bc      = (float*)(aux + 4096);                   // 32KB
  float*          dbv     = (float*)(aux + 36864);                  // 256B
  float*          dbu     = (float*)(aux + 37120);                  // 1KB
  __hip_bfloat16* embedC  = (__hip_bfloat16*)(aux + 65536);         // 512KB
  __hip_bfloat16* dec_VTC = (__hip_bfloat16*)(aux + 589824);        // 128KB
  __hip_bfloat16* dec_UC  = (__hip_bfloat16*)(aux + 720896);        // 32KB
  __hip_bfloat16* H1ring  = (__hip_bfloat16*)(aux + 1048576);       // 512KB
  unsigned*       bar     = (unsigned*)(aux + 1572864);             // 1KB (256 slots)
  __hip_bfloat16* R       = (__hip_bfloat16*)(aux + 2097152);       // 2MB
  __hip_bfloat16* H1big   = (__hip_bfloat16*)(ws + 68 * M);         // [68,100MB)

  (void)in_sizes; (void)n_in; (void)out_size;

  // big mode: t-unique H1 (fresh addresses) -> all H reads L2-cached
  const int big = (ws_size >= (size_t)100 * M);
  __hip_bfloat16* H1 = big ? H1big : H1ring;
  const int h1mask = big ? 255 : 3;
  const int cmode  = big ? 1 : 0;

  hipFuncSetAttribute((const void*)k_lstm,
                      hipFuncAttributeMaxDynamicSharedMemorySize, 140288);

  k_detect<<<1, 256, 0, stream>>>((const unsigned short*)embed, flags);
  k_cvt_b<<<256, 256, 0, stream>>>(embed,  embedC,  256 * 1024, flags);
  k_cvt_b<<<64,  256, 0, stream>>>(dec_VT, dec_VTC, 64 * 1024,  flags);
  k_cvt_b<<<16,  256, 0, stream>>>(dec_U,  dec_UC,  256 * 64,   flags);
  k_cvt_f<<<1,   64,  0, stream>>>(dec_bVT, dbv, 64,  flags);
  k_cvt_f<<<1,   256, 0, stream>>>(dec_bU,  dbu, 256, flags);
  k_combine<<<4096, 256, 0, stream>>>(U_ih, U_hh, VT_ih, VT_hh, Wc, flags);
  k_bias   <<<2048, 256, 0, stream>>>(bVT_ih, U_ih, bU_ih, bVT_hh, U_hh, bU_hh, bc, flags);
  k_init   <<<1, 256, 0, stream>>>(bar);
  k_lstm   <<<256, 256, 140288, stream>>>(tokens, embedC, Wc, bc, H1, H2, bar,
                                          h1mask, cmode);
  k_dec1   <<<256, 256, 0, stream>>>(H2, dec_VTC, dbv, R);
  k_dec2   <<<64, 256, 0, stream>>>(R, dec_UC, dbu, d_out, flags);
}

// Round 5
// 3573.545 us; speedup vs baseline: 1.7541x; 1.1356x over previous
//
#include <hip/hip_runtime.h>
#include <hip/hip_bf16.h>

// LowRankNextCharacterLSTM on MI355X (gfx950). Inputs fp32 (runtime-detected,
// canonicalized to bf16); output fp32 (mode-matched store).
//
// Algebra: R_GATE == HIDDEN -> fold W = U@VT ([4096,1024]),
// b = bU_ih + bU_hh + bVT_ih@U_ih^T + bVT_hh@U_hh^T; then
//   gates = x @ W_ih^T + h @ W_hh^T + b.
// Recurrence: ONE persistent kernel, 256 WGs (1 block/CU via 137KB LDS),
// weights staged to LDS once, two layers pipelined, 257 grid barriers.
//
// Round 13: TREE BARRIER. Round-12 budget: step=14.6us, of which MFMA 0.9 +
// VALU 1.0 + deep-pipelined loads ~3 + drain ~1 -> ~9us unexplained = the
// all-poll-all barrier: 256 WGs x 64 lanes re-reading the SAME 16 lines via
// agent-scope (LLC-direct, uncacheable) atomics = ~2k same-line LLC requests
// per sweep -> LLC serialization. Replaced with a 3-stage tree:
//   arrive: WG w stores gen to slot [(w&7)*32 + (w>>3)]  (group-packed)
//   root:   leader (w<8) polls its group's 32 slots (16 lanes x u64,
//           fan-in 33/line), then stores rootflag[g] (one 32B line)
//   release:leaders poll the 8 rootflags (32 req/line), then store a
//           per-group release word on its OWN line; non-leaders poll it
//           with ONE lane (fan-in 31/line).
// 3 sequential LLC round trips ~2-2.5us vs ~9us. Monotone gens, no resets;
// drain-before-arrive visibility identical to the flat barrier.
//
// Round 12/11: sched_barrier(0) pins the 64-load A-strip register prefetch
// (VGPR 44 -> 160, ~28 loads in flight, 2-batch pipeline).
// Coherence by address freshness (round 9):
//   - every H tile is written to a t-unique address (H2 [t]; H1 [256] when
//     ws_size >= 100MB, else legacy 4-deep ring + bypass-atomic loads),
//   - producers store write-through (sc0 sc1) and drain before the arrival
//     flag, so the LLC holds the data before any reader can miss-fetch it,
//   - a fresh line can therefore never be stale in any XCD's L1/L2.

#define B_SZ   64
#define T_SEQ  256
#define HID    1024
#define G4     4096

typedef __attribute__((ext_vector_type(8))) short bf16x8;
typedef __attribute__((ext_vector_type(4))) float f32x4;
typedef __attribute__((ext_vector_type(4))) short bf16x4;
typedef unsigned long long u64;

__device__ __forceinline__ f32x4 mfma16(bf16x8 a, bf16x8 b, f32x4 c) {
  return __builtin_amdgcn_mfma_f32_16x16x32_bf16(a, b, c, 0, 0, 0);
}
__device__ __forceinline__ float sigm(float x)  { return 1.f / (1.f + __expf(-x)); }
__device__ __forceinline__ float tanh_(float x) { return 2.f / (1.f + __expf(-2.f * x)) - 1.f; }
__device__ __forceinline__ f32x4 fzero() { f32x4 z; z[0]=0.f; z[1]=0.f; z[2]=0.f; z[3]=0.f; return z; }

// L2-bypass (agent-coherent) 16B load as 2x64-bit relaxed atomics
__device__ __forceinline__ bf16x8 lda(const __hip_bfloat16* p) {
  const u64* q = (const u64*)p;
  union { u64 u[2]; bf16x8 v; } r;
  r.u[0] = __hip_atomic_load(q,     __ATOMIC_RELAXED, __HIP_MEMORY_SCOPE_AGENT);
  r.u[1] = __hip_atomic_load(q + 1, __ATOMIC_RELAXED, __HIP_MEMORY_SCOPE_AGENT);
  return r.v;
}

// mode: 1 = inputs stored fp32, 0 = bf16
__device__ __forceinline__ float ld1(const void* p, size_t i, int mode) {
  return mode ? ((const float*)p)[i]
              : __bfloat162float(((const __hip_bfloat16*)p)[i]);
}
__device__ __forceinline__ bf16x8 ld8(const void* p, size_t i, int mode) {
  if (mode) {
    const float* f = (const float*)p + i;
    float4 a = *(const float4*)f;
    float4 b = *(const float4*)(f + 4);
    union { bf16x8 v; __hip_bfloat16 h[8]; } u;
    u.h[0] = __float2bfloat16(a.x); u.h[1] = __float2bfloat16(a.y);
    u.h[2] = __float2bfloat16(a.z); u.h[3] = __float2bfloat16(a.w);
    u.h[4] = __float2bfloat16(b.x); u.h[5] = __float2bfloat16(b.y);
    u.h[6] = __float2bfloat16(b.z); u.h[7] = __float2bfloat16(b.w);
    return u.v;
  }
  return *(const bf16x8*)((const __hip_bfloat16*)p + i);
}

// ---------------------------------------------------------------------------
__global__ void k_detect(const unsigned short* __restrict__ e, int* __restrict__ flags) {
  __shared__ int cnt;
  if (threadIdx.x == 0) cnt = 0;
  __syncthreads();
  int c = 0;
  for (int i = threadIdx.x; i < 2048; i += 256) {
    unsigned int bits = ((unsigned int)e[2 * i]) << 16;
    float f = __uint_as_float(bits);
    if (!isfinite(f) || fabsf(f) > 1e10f) ++c;
  }
  atomicAdd(&cnt, c);
  __syncthreads();
  if (threadIdx.x == 0) flags[0] = (cnt > 8) ? 1 : 0;
}

__global__ void k_cvt_b(const void* __restrict__ src, __hip_bfloat16* __restrict__ dst,
                        int n, const int* __restrict__ flags) {
  const int mode = flags[0];
  for (int i = blockIdx.x * blockDim.x + threadIdx.x; i < n; i += gridDim.x * blockDim.x)
    dst[i] = mode ? __float2bfloat16(((const float*)src)[i])
                  : ((const __hip_bfloat16*)src)[i];
}
__global__ void k_cvt_f(const void* __restrict__ src, float* __restrict__ dst,
                        int n, const int* __restrict__ flags) {
  const int mode = flags[0];
  for (int i = blockIdx.x * blockDim.x + threadIdx.x; i < n; i += gridDim.x * blockDim.x)
    dst[i] = mode ? ((const float*)src)[i]
                  : __bfloat162float(((const __hip_bfloat16*)src)[i]);
}

// zero the barrier region: 256 arrive + rootflags + per-group release lines
__global__ void k_init(unsigned* bar) {
  for (int i = threadIdx.x; i < 1024; i += 256) bar[i] = 0u;
}

// ---------------------------------------------------------------------------
// K2: Wc[Mid] = U @ VT  (Mid = L*2+typ; typ 0=ih 1=hh), bf16 out, f32 acc
// ---------------------------------------------------------------------------
__global__ void __launch_bounds__(256) k_combine(
    const void* __restrict__ U_ih, const void* __restrict__ U_hh,
    const void* __restrict__ VT_ih, const void* __restrict__ VT_hh,
    __hip_bfloat16* __restrict__ Wc, const int* __restrict__ flags)
{
  __shared__ __hip_bfloat16 sB[4 * 64 * 8];
  const int mode = flags[0];
  const int idx  = blockIdx.x;
  const int Mid  = idx >> 10;
  const int rem  = idx & 1023;
  const int gblk = rem >> 4, kblk = rem & 15;
  const int L = Mid >> 1, typ = Mid & 1;
  const void* U  = typ ? U_hh  : U_ih;
  const void* VT = typ ? VT_hh : VT_ih;
  const size_t Uoff  = (size_t)L * G4 * HID;
  const size_t VToff = (size_t)L * HID * HID;
  const int tid = threadIdx.x, lane = tid & 63, wv = tid >> 6;

  f32x4 acc[4];
  for (int i = 0; i < 4; ++i) acc[i] = fzero();

  const int r_local = tid >> 3;
  const int kk8     = (tid & 7) * 8;

  for (int r0 = 0; r0 < HID; r0 += 32) {
    union { bf16x8 v; __hip_bfloat16 h[8]; } u;
    u.v = ld8(VT, VToff + (size_t)(r0 + r_local) * HID + kblk * 64 + kk8, mode);
    __syncthreads();
    #pragma unroll
    for (int j = 0; j < 8; ++j) {
      int k_local = kk8 + j;
      int tile = k_local >> 4;
      int ln   = ((r_local >> 3) << 4) | (k_local & 15);
      sB[(tile * 64 + ln) * 8 + (r_local & 7)] = u.h[j];
    }
    __syncthreads();
    bf16x8 a = ld8(U, Uoff + (size_t)(gblk * 64 + wv * 16 + (lane & 15)) * HID
                          + r0 + (lane >> 4) * 8, mode);
    #pragma unroll
    for (int nt = 0; nt < 4; ++nt) {
      bf16x8 b = *(const bf16x8*)(sB + (nt * 64 + lane) * 8);
      acc[nt] = mfma16(a, b, acc[nt]);
    }
  }
  #pragma unroll
  for (int nt = 0; nt < 4; ++nt)
    #pragma unroll
    for (int r = 0; r < 4; ++r) {
      int g = gblk * 64 + wv * 16 + (lane >> 4) * 4 + r;
      int k = kblk * 64 + nt * 16 + (lane & 15);
      Wc[((size_t)Mid * G4 + g) * HID + k] = __float2bfloat16(acc[nt][r]);
    }
}

// ---------------------------------------------------------------------------
// K3: bc[L][g] = bU_ih + bU_hh + bVT_ih@U_ih^T + bVT_hh@U_hh^T   (f32)
// ---------------------------------------------------------------------------
__global__ void __launch_bounds__(256) k_bias(
    const void* __restrict__ bVT_ih, const void* __restrict__ U_ih,
    const void* __restrict__ bU_ih,
    const void* __restrict__ bVT_hh, const void* __restrict__ U_hh,
    const void* __restrict__ bU_hh,
    float* __restrict__ bc, const int* __restrict__ flags)
{
  const int mode  = flags[0];
  const int g_all = blockIdx.x * 4 + (threadIdx.x >> 6);
  const int lane  = threadIdx.x & 63;
  const int L = g_all >> 12, g = g_all & 4095;
  const size_t ub = (size_t)(L * G4 + g) * HID + lane * 16;
  const size_t vb = (size_t)L * HID + lane * 16;
  float s = 0.f;
  #pragma unroll
  for (int c = 0; c < 16; ++c)
    s += ld1(bVT_ih, vb + c, mode) * ld1(U_ih, ub + c, mode)
       + ld1(bVT_hh, vb + c, mode) * ld1(U_hh, ub + c, mode);
  for (int off = 32; off; off >>= 1) s += __shfl_down(s, off);
  if (lane == 0)
    bc[g_all] = s + ld1(bU_ih, L * G4 + g, mode) + ld1(bU_hh, L * G4 + g, mode);
}

// ---------------------------------------------------------------------------
// K4: persistent pipelined LSTM. 256 WGs; WG w: L=w>>7, jg=w&127 (h cols
// [8jg,8jg+8)). Weights in LDS once (B-frag order). waves 0,1 = x-path,
// waves 2,3 = h-path. Macro-step s: L0 does t=s, L1 does t=s-1.
// cmode=1: H1/H2 reads are plain L2-cached loads (t-unique addresses keep
// them coherent). cmode=0: legacy bypass-atomic reads of the 4-deep H1 ring.
// ---------------------------------------------------------------------------
__global__ void __launch_bounds__(256, 1) k_lstm(
    const int* __restrict__ tokens, const __hip_bfloat16* __restrict__ embedC,
    const __hip_bfloat16* __restrict__ Wc, const float* __restrict__ bc,
    __hip_bfloat16* __restrict__ H1, __hip_bfloat16* __restrict__ H2,
    unsigned* bar, const int h1mask, const int cmode)
{
  extern __shared__ char smem[];
  __hip_bfloat16* Wl = (__hip_bfloat16*)smem;            // 128KB, B-frag order
  f32x4* Xex = (f32x4*)(smem + 131072);                  // 8KB exchange
  __hip_bfloat16* Hs = (__hip_bfloat16*)(smem + 139264); // 1KB h staging [64][8]

  const int tid  = threadIdx.x;
  const int lane = tid & 63, wv = tid >> 6;
  const int w    = blockIdx.x;
  const int L    = w >> 7, jg = w & 127;
  const int mat  = wv >> 1, mhalf = wv & 1;         // 0 = x-path, 1 = h-path

  // stage weight slices into LDS once; slot q = [mat(1)][ks(5)][tile(1)][ln(6)]
  for (int q = tid; q < 8192; q += 256) {
    int m_ = q >> 12, ks = (q >> 7) & 31, tl = (q >> 6) & 1, ln = q & 63;
    int n_local = tl * 16 + (ln & 15);
    int g = (n_local >> 3) * 1024 + jg * 8 + (n_local & 7);
    int k = ks * 32 + (ln >> 4) * 8;
    *(bf16x8*)(Wl + (size_t)q * 8) =
        *(const bf16x8*)(Wc + (((size_t)(L * 2 + m_) * G4 + g) << 10) + k);
  }
  const int nb = lane & 7;
  const float b_i = bc[L * G4 +        jg * 8 + nb];
  const float b_f = bc[L * G4 + 1024 + jg * 8 + nb];
  const float b_g = bc[L * G4 + 2048 + jg * 8 + nb];
  const float b_o = bc[L * G4 + 3072 + jg * 8 + nb];
  __syncthreads();

  float cst[2][4] = {{0.f,0.f,0.f,0.f},{0.f,0.f,0.f,0.f}};
  const int m0 = mhalf * 32 + (lane & 15);
  const int ko = (lane >> 4) * 8;
  const __hip_bfloat16* wbase = Wl + mat * 32768;
  unsigned gen = 0;

  // tree-barrier constants
  const int bg   = w & 7;          // contention group (presumed XCD)
  const int bsub = w >> 3;         // slot within group

  for (int s = 0; s <= T_SEQ; ++s) {
    const int t = s - L;
    const bool act = (t >= 0 && t < T_SEQ);          // block-uniform
    if (act) {
      f32x4 acc00 = fzero(), acc01 = fzero(), acc10 = fzero(), acc11 = fzero();
      bool doGemm = true, cached = false;
      const __hip_bfloat16 *A0 = nullptr, *A1 = nullptr;
      if (mat == 0) {
        if (L == 0) {                                // embed: read-only, cached
          A0 = embedC + ((size_t)tokens[m0 * T_SEQ + t] << 10);
          A1 = embedC + ((size_t)tokens[(m0 + 16) * T_SEQ + t] << 10);
          cached = true;
        } else {                                     // H1[t]: fresh address
          A0 = H1 + ((((size_t)(t & h1mask)) * 64 + m0) << 10);
          A1 = A0 + ((size_t)16 << 10);
          cached = (cmode != 0);
        }
      } else {
        if (t == 0) doGemm = false;                  // h_{-1} = 0
        else {
          if (L == 0) {                              // H1[t-1]: fresh address
            A0 = H1 + ((((size_t)((t - 1) & h1mask)) * 64 + m0) << 10);
            cached = (cmode != 0);
          } else {                                   // H2[t-1]: always t-unique
            A0 = H2 + (((size_t)(t - 1) * 64 + m0) << 10);
            cached = true;
          }
          A1 = A0 + ((size_t)16 << 10);
        }
      }
      if (doGemm) {
        if (cached) {
          // Register-prefetch the full A strip: 64 x 16B loads issued
          // back-to-back; sched_barrier(0) pins the schedule so the loads
          // stay in flight (VGPR 160, ~2-batch pipeline).
          bf16x8 p0[32], p1[32];
          #pragma unroll
          for (int i = 0; i < 32; ++i) {
            p0[i] = *(const bf16x8*)(A0 + i * 32 + ko);
            p1[i] = *(const bf16x8*)(A1 + i * 32 + ko);
          }
          __builtin_amdgcn_sched_barrier(0);
          #pragma unroll
          for (int ks = 0; ks < 32; ++ks) {
            bf16x8 b0 = *(const bf16x8*)(wbase + (ks * 2 + 0) * 512 + lane * 8);
            bf16x8 b1 = *(const bf16x8*)(wbase + (ks * 2 + 1) * 512 + lane * 8);
            acc00 = mfma16(p0[ks], b0, acc00);
            acc01 = mfma16(p0[ks], b1, acc01);
            acc10 = mfma16(p1[ks], b0, acc10);
            acc11 = mfma16(p1[ks], b1, acc11);
          }
        } else {
          #pragma unroll 4
          for (int ks = 0; ks < 32; ++ks) {
            bf16x8 a0 = lda(A0 + ks * 32 + ko);
            bf16x8 a1 = lda(A1 + ks * 32 + ko);
            bf16x8 b0 = *(const bf16x8*)(wbase + (ks * 2 + 0) * 512 + lane * 8);
            bf16x8 b1 = *(const bf16x8*)(wbase + (ks * 2 + 1) * 512 + lane * 8);
            acc00 = mfma16(a0, b0, acc00);
            acc01 = mfma16(a0, b1, acc01);
            acc10 = mfma16(a1, b0, acc10);
            acc11 = mfma16(a1, b1, acc11);
          }
        }
      }
      if (mat == 0) {
        Xex[(mhalf * 4 + 0) * 64 + lane] = acc00;
        Xex[(mhalf * 4 + 1) * 64 + lane] = acc01;
        Xex[(mhalf * 4 + 2) * 64 + lane] = acc10;
        Xex[(mhalf * 4 + 3) * 64 + lane] = acc11;
      }
      __syncthreads();
      if (mat == 1) {                                // gates -> c,h -> LDS tile
        #pragma unroll
        for (int mt = 0; mt < 2; ++mt) {
          f32x4 aT0 = mt ? acc10 : acc00;
          f32x4 aT1 = mt ? acc11 : acc01;
          f32x4 gx0 = Xex[(mhalf * 4 + mt * 2 + 0) * 64 + lane];
          f32x4 gx1 = Xex[(mhalf * 4 + mt * 2 + 1) * 64 + lane];
          #pragma unroll
          for (int r = 0; r < 4; ++r) {
            float v0 = aT0[r] + gx0[r];
            float v1 = aT1[r] + gx1[r];
            float p0 = __shfl_xor(v0, 8);
            float p1 = __shfl_xor(v1, 8);
            if ((lane & 15) < 8) {
              float iv = sigm(v0 + b_i);
              float fv = sigm(p0 + b_f);
              float gv = tanh_(v1 + b_g);
              float ov = sigm(p1 + b_o);
              float c  = fv * cst[mt][r] + iv * gv;
              cst[mt][r] = c;
              float h  = ov * tanh_(c);
              int m = mhalf * 32 + mt * 16 + (lane >> 4) * 4 + r;
              Hs[m * 8 + (lane & 15)] = __float2bfloat16(h);
            }
          }
        }
      }
      __syncthreads();                               // Hs tile complete
      // flush Hs -> global as 8B agent-coherent (write-through) stores
      if (tid < 128) {
        char* HoutB = (L == 0) ? (char*)(H1 + (((size_t)(t & h1mask)) << 16))
                               : (char*)(H2 + (((size_t)t) << 16));
        u64 v = ((const u64*)Hs)[tid];
        u64* dst = (u64*)(HoutB + ((size_t)(tid >> 1) << 11) + (jg << 4) + ((tid & 1) << 3));
        __hip_atomic_store(dst, v, __ATOMIC_RELAXED, __HIP_MEMORY_SCOPE_AGENT);
      }
    }
    // ---- grid barrier: 3-stage tree (arrive -> root -> release) ----
    __syncthreads();                                 // drains all waves' stores
    ++gen;
    if (wv == 0) {
      if (lane == 0)
        __hip_atomic_store(&bar[bg * 32 + bsub], gen,
                           __ATOMIC_RELAXED, __HIP_MEMORY_SCOPE_AGENT);
      if (bsub == 0) {                // leader of group bg (w = bg < 8)
        // stage 2: aggregate this group's 32 arrival slots (16 x u64)
        const u64* gs = (const u64*)(bar + bg * 32);
        const int li = lane & 15;
        for (;;) {
          u64 v = __hip_atomic_load(&gs[li], __ATOMIC_RELAXED, __HIP_MEMORY_SCOPE_AGENT);
          bool ok = ((unsigned)v >= gen) && ((unsigned)(v >> 32) >= gen);
          if (__all(ok)) break;
          __builtin_amdgcn_s_sleep(1);
        }
        if (lane == 0)
          __hip_atomic_store(&bar[256 + bg], gen,
                             __ATOMIC_RELAXED, __HIP_MEMORY_SCOPE_AGENT);
        // stage 3: wait for all 8 roots (one 32B line), then release group
        const u64* rf = (const u64*)(bar + 256);
        const int ri = lane & 3;
        for (;;) {
          u64 v = __hip_atomic_load(&rf[ri], __ATOMIC_RELAXED, __HIP_MEMORY_SCOPE_AGENT);
          bool ok = ((unsigned)v >= gen) && ((unsigned)(v >> 32) >= gen);
          if (__all(ok)) break;
          __builtin_amdgcn_s_sleep(1);
        }
        if (lane == 0)
          __hip_atomic_store(&bar[512 + bg * 16], gen,
                             __ATOMIC_RELAXED, __HIP_MEMORY_SCOPE_AGENT);
      } else {
        // non-leader: single lane polls the group's release word
        if (lane == 0) {
          for (;;) {
            unsigned v = __hip_atomic_load(&bar[512 + bg * 16],
                                           __ATOMIC_RELAXED, __HIP_MEMORY_SCOPE_AGENT);
            if (v >= gen) break;
            __builtin_amdgcn_s_sleep(2);
          }
        }
      }
    }
    __syncthreads();                                 // release compute waves
  }
}

// ---------------------------------------------------------------------------
// K5: R(t,b,n) = H2[t][b][:] @ dec_VT[n][:] + dec_bVT[n]   (bf16)
// ---------------------------------------------------------------------------
__global__ void __launch_bounds__(256) k_dec1(
    const __hip_bfloat16* __restrict__ H2, const __hip_bfloat16* __restrict__ dec_VTC,
    const float* __restrict__ dbv, __hip_bfloat16* __restrict__ R)
{
  const int t = blockIdx.x;
  const int lane = threadIdx.x & 63, wv = threadIdx.x >> 6;
  const __hip_bfloat16* A = H2 + ((size_t)t << 16) + ((size_t)(wv * 16 + (lane & 15)) << 10);
  const int ko = (lane >> 4) * 8;
  f32x4 acc[4];
  for (int i = 0; i < 4; ++i) acc[i] = fzero();
  for (int ks = 0; ks < 32; ++ks) {
    bf16x8 a = *(const bf16x8*)(A + ks * 32 + ko);
    #pragma unroll
    for (int nt = 0; nt < 4; ++nt) {
      bf16x8 b = *(const bf16x8*)(dec_VTC + ((size_t)(nt * 16 + (lane & 15)) << 10) + ks * 32 + ko);
      acc[nt] = mfma16(a, b, acc[nt]);
    }
  }
  #pragma unroll
  for (int nt = 0; nt < 4; ++nt) {
    int n = nt * 16 + (lane & 15);
    float bias = dbv[n];
    #pragma unroll
    for (int r = 0; r < 4; ++r) {
      int b_row = wv * 16 + (lane >> 4) * 4 + r;
      R[((size_t)t << 12) + (size_t)b_row * 64 + n] = __float2bfloat16(acc[nt][r] + bias);
    }
  }
}

// ---------------------------------------------------------------------------
// K6: out[b][v][t] = R(t,b,:) @ dec_U[v][:] + dec_bU[v]; store dtype = mode
// ---------------------------------------------------------------------------
__global__ void __launch_bounds__(256) k_dec2(
    const __hip_bfloat16* __restrict__ R, const __hip_bfloat16* __restrict__ dec_UC,
    const float* __restrict__ dbu, void* __restrict__ out,
    const int* __restrict__ flags)
{
  const int mode = flags[0];
  const int bblk = blockIdx.x >> 4, tblk = blockIdx.x & 15;
  const int lane = threadIdx.x & 63, wv = threadIdx.x >> 6;
  const int ko  = (lane >> 4) * 8;
  const int t_l = lane & 15;
  for (int bi = 0; bi < 4; ++bi) {
    const int b = bblk * 16 + wv * 4 + bi;
    f32x4 acc[16];
    for (int i = 0; i < 16; ++i) acc[i] = fzero();
    #pragma unroll
    for (int ks = 0; ks < 2; ++ks) {
      bf16x8 a = *(const bf16x8*)(R + (((size_t)(tblk * 16 + t_l) * 64 + b) << 6)
                                    + ks * 32 + ko);
      #pragma unroll
      for (int nt = 0; nt < 16; ++nt) {
        bf16x8 bb = *(const bf16x8*)(dec_UC + ((size_t)(nt * 16 + t_l) << 6) + ks * 32 + ko);
        acc[nt] = mfma16(a, bb, acc[nt]);
      }
    }
    #pragma unroll
    for (int nt = 0; nt < 16; ++nt) {
      int v = nt * 16 + t_l;
      float bias = dbu[v];
      size_t off = (size_t)b * 65536 + (size_t)v * 256 + tblk * 16 + (lane >> 4) * 4;
      if (mode) {
        float4 st;
        st.x = acc[nt][0] + bias; st.y = acc[nt][1] + bias;
        st.z = acc[nt][2] + bias; st.w = acc[nt][3] + bias;
        *(float4*)((float*)out + off) = st;
      } else {
        union { bf16x4 v4; __hip_bfloat16 h[4]; } u;
        #pragma unroll
        for (int r = 0; r < 4; ++r) u.h[r] = __float2bfloat16(acc[nt][r] + bias);
        *(bf16x4*)((__hip_bfloat16*)out + off) = u.v4;
      }
    }
  }
}

// ---------------------------------------------------------------------------
extern "C" void kernel_launch(void* const* d_in, const int* in_sizes, int n_in,
                              void* d_out, int out_size, void* d_ws, size_t ws_size,
                              hipStream_t stream)
{
  const int* tokens  = (const int*)d_in[0];
  const void* embed  = d_in[1];
  const void* VT_ih  = d_in[2];
  const void* bVT_ih = d_in[3];
  const void* U_ih   = d_in[4];
  const void* bU_ih  = d_in[5];
  const void* VT_hh  = d_in[6];
  const void* bVT_hh = d_in[7];
  const void* U_hh   = d_in[8];
  const void* bU_hh  = d_in[9];
  const void* dec_VT = d_in[10];
  const void* dec_bVT= d_in[11];
  const void* dec_U  = d_in[12];
  const void* dec_bU = d_in[13];

  char* ws = (char*)d_ws;
  const size_t M = 1024 * 1024;
  // ws layout (100 MB total in big mode, 68 MB in fallback):
  __hip_bfloat16* Wc      = (__hip_bfloat16*)ws;                    // [0,32MB)
  __hip_bfloat16* H2      = (__hip_bfloat16*)(ws + 32 * M);         // [32,64MB)
  char* aux = ws + 64 * M;                                          // [64,68MB)
  int*            flags   = (int*)aux;                              // 256B
  float*          bc      = (float*)(aux + 4096);                   // 32KB
  float*          dbv     = (float*)(aux + 36864);                  // 256B
  float*          dbu     = (float*)(aux + 37120);                  // 1KB
  __hip_bfloat16* embedC  = (__hip_bfloat16*)(aux + 65536);         // 512KB
  __hip_bfloat16* dec_VTC = (__hip_bfloat16*)(aux + 589824);        // 128KB
  __hip_bfloat16* dec_UC  = (__hip_bfloat16*)(aux + 720896);        // 32KB
  __hip_bfloat16* H1ring  = (__hip_bfloat16*)(aux + 1048576);       // 512KB
  unsigned*       bar     = (unsigned*)(aux + 1572864);             // 4KB (tree)
  __hip_bfloat16* R       = (__hip_bfloat16*)(aux + 2097152);       // 2MB
  __hip_bfloat16* H1big   = (__hip_bfloat16*)(ws + 68 * M);         // [68,100MB)

  (void)in_sizes; (void)n_in; (void)out_size;

  // big mode: t-unique H1 (fresh addresses) -> all H reads L2-cached
  const int big = (ws_size >= (size_t)100 * M);
  __hip_bfloat16* H1 = big ? H1big : H1ring;
  const int h1mask = big ? 255 : 3;
  const int cmode  = big ? 1 : 0;

  hipFuncSetAttribute((const void*)k_lstm,
                      hipFuncAttributeMaxDynamicSharedMemorySize, 140288);

  k_detect<<<1, 256, 0, stream>>>((const unsigned short*)embed, flags);
  k_cvt_b<<<256, 256, 0, stream>>>(embed,  embedC,  256 * 1024, flags);
  k_cvt_b<<<64,  256, 0, stream>>>(dec_VT, dec_VTC, 64 * 1024,  flags);
  k_cvt_b<<<16,  256, 0, stream>>>(dec_U,  dec_UC,  256 * 64,   flags);
  k_cvt_f<<<1,   64,  0, stream>>>(dec_bVT, dbv, 64,  flags);
  k_cvt_f<<<1,   256, 0, stream>>>(dec_bU,  dbu, 256, flags);
  k_combine<<<4096, 256, 0, stream>>>(U_ih, U_hh, VT_ih, VT_hh, Wc, flags);
  k_bias   <<<2048, 256, 0, stream>>>(bVT_ih, U_ih, bU_ih, bVT_hh, U_hh, bU_hh, bc, flags);
  k_init   <<<1, 256, 0, stream>>>(bar);
  k_lstm   <<<256, 256, 140288, stream>>>(tokens, embedC, Wc, bc, H1, H2, bar,
                                          h1mask, cmode);
  k_dec1   <<<256, 256, 0, stream>>>(H2, dec_VTC, dbv, R);
  k_dec2   <<<64, 256, 0, stream>>>(R, dec_UC, dbu, d_out, flags);
}

// Round 6
// 3288.354 us; speedup vs baseline: 1.9063x; 1.0867x over previous
//
#include <hip/hip_runtime.h>
#include <hip/hip_bf16.h>

// LowRankNextCharacterLSTM on MI355X (gfx950). Inputs fp32 (runtime-detected,
// canonicalized to bf16); output fp32 (mode-matched store).
//
// Algebra: R_GATE == HIDDEN -> fold W = U@VT ([4096,1024]),
// b = bU_ih + bU_hh + bVT_ih@U_ih^T + bVT_hh@U_hh^T; then
//   gates = x @ W_ih^T + h @ W_hh^T + b.
// Recurrence: ONE persistent kernel, 256 WGs (1 block/CU via 137KB LDS),
// weights staged to LDS once.
//
// Round 14: DECOUPLED PER-LAYER BARRIERS (flat, 3 LLC round-trips).
// L0 depends only on L0 (x = read-only embed, h = own H1[t-1]); L1 needs
// all-L0 >= t+1 (for H1[t]) and all-L1 >= t (for H2[t-1]). Each layer:
//   arrive:  WG w stores t+1 to bar[w] after its flush drains.
//   permit:  leader (jg==0) wave0 sweeps its layer's 128 slots in ONE wave
//            sweep (64 lanes x u64), plus the cross-layer condition
//            (L1: minL0 >= t+1; L0 fallback throttle: minL1+3 >= t for the
//            4-deep H1 ring), then publishes X=t+1 to 8 replicated lines.
//   poll:    members poll their group's line with lane 0. L0 x-waves never
//            poll (embed is read-only) -> x-GEMM runs in the barrier shadow;
//            L0 runs ahead of L1, so L1's cross check is pre-satisfied.
// vs round-13 tree (4.5 RTs + joint 256-WG skew): 3 RTs + 128-WG skew,
// decorrelated layer phases.
//
// Round 12/11: sched_barrier(0) pins the 64-load A-strip register prefetch
// (VGPR 160, ~2-batch deep pipeline).
// Coherence by address freshness (round 9):
//   - every H tile is written to a t-unique address (H2 [t]; H1 [256] when
//     ws_size >= 100MB, else legacy 4-deep ring + bypass-atomic loads),
//   - producers store write-through agent-scope and drain before the arrival
//     flag, so the LLC holds the data before any reader can miss-fetch it,
//   - a fresh line can therefore never be stale in any XCD's L1/L2.

#define B_SZ   64
#define T_SEQ  256
#define HID    1024
#define G4     4096

typedef __attribute__((ext_vector_type(8))) short bf16x8;
typedef __attribute__((ext_vector_type(4))) float f32x4;
typedef __attribute__((ext_vector_type(4))) short bf16x4;
typedef unsigned long long u64;

__device__ __forceinline__ f32x4 mfma16(bf16x8 a, bf16x8 b, f32x4 c) {
  return __builtin_amdgcn_mfma_f32_16x16x32_bf16(a, b, c, 0, 0, 0);
}
__device__ __forceinline__ float sigm(float x)  { return 1.f / (1.f + __expf(-x)); }
__device__ __forceinline__ float tanh_(float x) { return 2.f / (1.f + __expf(-2.f * x)) - 1.f; }
__device__ __forceinline__ f32x4 fzero() { f32x4 z; z[0]=0.f; z[1]=0.f; z[2]=0.f; z[3]=0.f; return z; }

// L2-bypass (agent-coherent) 16B load as 2x64-bit relaxed atomics
__device__ __forceinline__ bf16x8 lda(const __hip_bfloat16* p) {
  const u64* q = (const u64*)p;
  union { u64 u[2]; bf16x8 v; } r;
  r.u[0] = __hip_atomic_load(q,     __ATOMIC_RELAXED, __HIP_MEMORY_SCOPE_AGENT);
  r.u[1] = __hip_atomic_load(q + 1, __ATOMIC_RELAXED, __HIP_MEMORY_SCOPE_AGENT);
  return r.v;
}

// mode: 1 = inputs stored fp32, 0 = bf16
__device__ __forceinline__ float ld1(const void* p, size_t i, int mode) {
  return mode ? ((const float*)p)[i]
              : __bfloat162float(((const __hip_bfloat16*)p)[i]);
}
__device__ __forceinline__ bf16x8 ld8(const void* p, size_t i, int mode) {
  if (mode) {
    const float* f = (const float*)p + i;
    float4 a = *(const float4*)f;
    float4 b = *(const float4*)(f + 4);
    union { bf16x8 v; __hip_bfloat16 h[8]; } u;
    u.h[0] = __float2bfloat16(a.x); u.h[1] = __float2bfloat16(a.y);
    u.h[2] = __float2bfloat16(a.z); u.h[3] = __float2bfloat16(a.w);
    u.h[4] = __float2bfloat16(b.x); u.h[5] = __float2bfloat16(b.y);
    u.h[6] = __float2bfloat16(b.z); u.h[7] = __float2bfloat16(b.w);
    return u.v;
  }
  return *(const bf16x8*)((const __hip_bfloat16*)p + i);
}

// ---------------------------------------------------------------------------
__global__ void k_detect(const unsigned short* __restrict__ e, int* __restrict__ flags) {
  __shared__ int cnt;
  if (threadIdx.x == 0) cnt = 0;
  __syncthreads();
  int c = 0;
  for (int i = threadIdx.x; i < 2048; i += 256) {
    unsigned int bits = ((unsigned int)e[2 * i]) << 16;
    float f = __uint_as_float(bits);
    if (!isfinite(f) || fabsf(f) > 1e10f) ++c;
  }
  atomicAdd(&cnt, c);
  __syncthreads();
  if (threadIdx.x == 0) flags[0] = (cnt > 8) ? 1 : 0;
}

__global__ void k_cvt_b(const void* __restrict__ src, __hip_bfloat16* __restrict__ dst,
                        int n, const int* __restrict__ flags) {
  const int mode = flags[0];
  for (int i = blockIdx.x * blockDim.x + threadIdx.x; i < n; i += gridDim.x * blockDim.x)
    dst[i] = mode ? __float2bfloat16(((const float*)src)[i])
                  : ((const __hip_bfloat16*)src)[i];
}
__global__ void k_cvt_f(const void* __restrict__ src, float* __restrict__ dst,
                        int n, const int* __restrict__ flags) {
  const int mode = flags[0];
  for (int i = blockIdx.x * blockDim.x + threadIdx.x; i < n; i += gridDim.x * blockDim.x)
    dst[i] = mode ? ((const float*)src)[i]
                  : __bfloat162float(((const __hip_bfloat16*)src)[i]);
}

// zero the barrier region: 256 arrive slots + replicated permit lines
__global__ void k_init(unsigned* bar) {
  for (int i = threadIdx.x; i < 1024; i += 256) bar[i] = 0u;
}

// ---------------------------------------------------------------------------
// K2: Wc[Mid] = U @ VT  (Mid = L*2+typ; typ 0=ih 1=hh), bf16 out, f32 acc
// ---------------------------------------------------------------------------
__global__ void __launch_bounds__(256) k_combine(
    const void* __restrict__ U_ih, const void* __restrict__ U_hh,
    const void* __restrict__ VT_ih, const void* __restrict__ VT_hh,
    __hip_bfloat16* __restrict__ Wc, const int* __restrict__ flags)
{
  __shared__ __hip_bfloat16 sB[4 * 64 * 8];
  const int mode = flags[0];
  const int idx  = blockIdx.x;
  const int Mid  = idx >> 10;
  const int rem  = idx & 1023;
  const int gblk = rem >> 4, kblk = rem & 15;
  const int L = Mid >> 1, typ = Mid & 1;
  const void* U  = typ ? U_hh  : U_ih;
  const void* VT = typ ? VT_hh : VT_ih;
  const size_t Uoff  = (size_t)L * G4 * HID;
  const size_t VToff = (size_t)L * HID * HID;
  const int tid = threadIdx.x, lane = tid & 63, wv = tid >> 6;

  f32x4 acc[4];
  for (int i = 0; i < 4; ++i) acc[i] = fzero();

  const int r_local = tid >> 3;
  const int kk8     = (tid & 7) * 8;

  for (int r0 = 0; r0 < HID; r0 += 32) {
    union { bf16x8 v; __hip_bfloat16 h[8]; } u;
    u.v = ld8(VT, VToff + (size_t)(r0 + r_local) * HID + kblk * 64 + kk8, mode);
    __syncthreads();
    #pragma unroll
    for (int j = 0; j < 8; ++j) {
      int k_local = kk8 + j;
      int tile = k_local >> 4;
      int ln   = ((r_local >> 3) << 4) | (k_local & 15);
      sB[(tile * 64 + ln) * 8 + (r_local & 7)] = u.h[j];
    }
    __syncthreads();
    bf16x8 a = ld8(U, Uoff + (size_t)(gblk * 64 + wv * 16 + (lane & 15)) * HID
                          + r0 + (lane >> 4) * 8, mode);
    #pragma unroll
    for (int nt = 0; nt < 4; ++nt) {
      bf16x8 b = *(const bf16x8*)(sB + (nt * 64 + lane) * 8);
      acc[nt] = mfma16(a, b, acc[nt]);
    }
  }
  #pragma unroll
  for (int nt = 0; nt < 4; ++nt)
    #pragma unroll
    for (int r = 0; r < 4; ++r) {
      int g = gblk * 64 + wv * 16 + (lane >> 4) * 4 + r;
      int k = kblk * 64 + nt * 16 + (lane & 15);
      Wc[((size_t)Mid * G4 + g) * HID + k] = __float2bfloat16(acc[nt][r]);
    }
}

// ---------------------------------------------------------------------------
// K3: bc[L][g] = bU_ih + bU_hh + bVT_ih@U_ih^T + bVT_hh@U_hh^T   (f32)
// ---------------------------------------------------------------------------
__global__ void __launch_bounds__(256) k_bias(
    const void* __restrict__ bVT_ih, const void* __restrict__ U_ih,
    const void* __restrict__ bU_ih,
    const void* __restrict__ bVT_hh, const void* __restrict__ U_hh,
    const void* __restrict__ bU_hh,
    float* __restrict__ bc, const int* __restrict__ flags)
{
  const int mode  = flags[0];
  const int g_all = blockIdx.x * 4 + (threadIdx.x >> 6);
  const int lane  = threadIdx.x & 63;
  const int L = g_all >> 12, g = g_all & 4095;
  const size_t ub = (size_t)(L * G4 + g) * HID + lane * 16;
  const size_t vb = (size_t)L * HID + lane * 16;
  float s = 0.f;
  #pragma unroll
  for (int c = 0; c < 16; ++c)
    s += ld1(bVT_ih, vb + c, mode) * ld1(U_ih, ub + c, mode)
       + ld1(bVT_hh, vb + c, mode) * ld1(U_hh, ub + c, mode);
  for (int off = 32; off; off >>= 1) s += __shfl_down(s, off);
  if (lane == 0)
    bc[g_all] = s + ld1(bU_ih, L * G4 + g, mode) + ld1(bU_hh, L * G4 + g, mode);
}

// ---------------------------------------------------------------------------
// K4: persistent pipelined LSTM, decoupled per-layer sync. 256 WGs; WG w:
// L=w>>7, jg=w&127 (h cols [8jg,8jg+8)). waves 0,1 = x-path, 2,3 = h-path.
// Each layer loops t=0..255. Permit protocol in header comment.
// ---------------------------------------------------------------------------
__global__ void __launch_bounds__(256, 1) k_lstm(
    const int* __restrict__ tokens, const __hip_bfloat16* __restrict__ embedC,
    const __hip_bfloat16* __restrict__ Wc, const float* __restrict__ bc,
    __hip_bfloat16* __restrict__ H1, __hip_bfloat16* __restrict__ H2,
    unsigned* bar, const int h1mask, const int cmode)
{
  extern __shared__ char smem[];
  __hip_bfloat16* Wl = (__hip_bfloat16*)smem;            // 128KB, B-frag order
  f32x4* Xex = (f32x4*)(smem + 131072);                  // 8KB exchange
  __hip_bfloat16* Hs = (__hip_bfloat16*)(smem + 139264); // 1KB h staging [64][8]

  const int tid  = threadIdx.x;
  const int lane = tid & 63, wv = tid >> 6;
  const int w    = blockIdx.x;
  const int L    = w >> 7, jg = w & 127;
  const int mat  = wv >> 1, mhalf = wv & 1;         // 0 = x-path, 1 = h-path
  const bool leaderWave = (jg == 0) && (wv == 0);

  // stage weight slices into LDS once; slot q = [mat(1)][ks(5)][tile(1)][ln(6)]
  for (int q = tid; q < 8192; q += 256) {
    int m_ = q >> 12, ks = (q >> 7) & 31, tl = (q >> 6) & 1, ln = q & 63;
    int n_local = tl * 16 + (ln & 15);
    int g = (n_local >> 3) * 1024 + jg * 8 + (n_local & 7);
    int k = ks * 32 + (ln >> 4) * 8;
    *(bf16x8*)(Wl + (size_t)q * 8) =
        *(const bf16x8*)(Wc + (((size_t)(L * 2 + m_) * G4 + g) << 10) + k);
  }
  const int nb = lane & 7;
  const float b_i = bc[L * G4 +        jg * 8 + nb];
  const float b_f = bc[L * G4 + 1024 + jg * 8 + nb];
  const float b_g = bc[L * G4 + 2048 + jg * 8 + nb];
  const float b_o = bc[L * G4 + 3072 + jg * 8 + nb];
  __syncthreads();

  float cst[2][4] = {{0.f,0.f,0.f,0.f},{0.f,0.f,0.f,0.f}};
  const int m0 = mhalf * 32 + (lane & 15);
  const int ko = (lane >> 4) * 8;
  const __hip_bfloat16* wbase = Wl + mat * 32768;
  unsigned* Xrel = bar + 256 + L * 128;     // 8 replicated permit lines

  for (int t = 0; t < T_SEQ; ++t) {
    // ---- permit: leader sweeps + publishes; members poll; L0 x-waves free --
    if (leaderWave) {
      const u64* own = (const u64*)bar + (L ? 64 : 0);
      const u64* oth = (const u64*)bar + (L ? 0 : 64);
      const unsigned need = (unsigned)t;
      for (;;) {
        u64 a = __hip_atomic_load(&own[lane], __ATOMIC_RELAXED, __HIP_MEMORY_SCOPE_AGENT);
        bool ok = ((unsigned)a >= need) && ((unsigned)(a >> 32) >= need);
        if (L == 1) {                 // x reads H1[t]: all L0 must be >= t+1
          u64 b = __hip_atomic_load(&oth[lane], __ATOMIC_RELAXED, __HIP_MEMORY_SCOPE_AGENT);
          ok = ok && ((unsigned)b >= need + 1) && ((unsigned)(b >> 32) >= need + 1);
        } else if (cmode == 0) {      // 4-deep H1 ring: don't outrun L1 by >3
          u64 b = __hip_atomic_load(&oth[lane], __ATOMIC_RELAXED, __HIP_MEMORY_SCOPE_AGENT);
          ok = ok && ((unsigned)b + 3u >= need) && ((unsigned)(b >> 32) + 3u >= need);
        }
        if (__all(ok)) break;
        __builtin_amdgcn_s_sleep(1);
      }
      if (lane < 8)
        __hip_atomic_store(&Xrel[lane * 16], (unsigned)(t + 1),
                           __ATOMIC_RELAXED, __HIP_MEMORY_SCOPE_AGENT);
    } else if (L == 1 || mat == 1) {
      if (lane == 0) {
        for (;;) {
          unsigned v = __hip_atomic_load(&Xrel[(w & 7) * 16],
                                         __ATOMIC_RELAXED, __HIP_MEMORY_SCOPE_AGENT);
          if (v >= (unsigned)(t + 1)) break;
          __builtin_amdgcn_s_sleep(2);
        }
      }
    }

    // ---- compute ----
    f32x4 acc00 = fzero(), acc01 = fzero(), acc10 = fzero(), acc11 = fzero();
    bool doGemm = true, cached = false;
    const __hip_bfloat16 *A0 = nullptr, *A1 = nullptr;
    if (mat == 0) {
      if (L == 0) {                                // embed: read-only, cached
        A0 = embedC + ((size_t)tokens[m0 * T_SEQ + t] << 10);
        A1 = embedC + ((size_t)tokens[(m0 + 16) * T_SEQ + t] << 10);
        cached = true;
      } else {                                     // H1[t]: fresh address
        A0 = H1 + ((((size_t)(t & h1mask)) * 64 + m0) << 10);
        A1 = A0 + ((size_t)16 << 10);
        cached = (cmode != 0);
      }
    } else {
      if (t == 0) doGemm = false;                  // h_{-1} = 0
      else {
        if (L == 0) {                              // H1[t-1]: fresh address
          A0 = H1 + ((((size_t)((t - 1) & h1mask)) * 64 + m0) << 10);
          cached = (cmode != 0);
        } else {                                   // H2[t-1]: always t-unique
          A0 = H2 + (((size_t)(t - 1) * 64 + m0) << 10);
          cached = true;
        }
        A1 = A0 + ((size_t)16 << 10);
      }
    }
    if (doGemm) {
      if (cached) {
        // Register-prefetch the full A strip; sched_barrier(0) pins it.
        bf16x8 p0[32], p1[32];
        #pragma unroll
        for (int i = 0; i < 32; ++i) {
          p0[i] = *(const bf16x8*)(A0 + i * 32 + ko);
          p1[i] = *(const bf16x8*)(A1 + i * 32 + ko);
        }
        __builtin_amdgcn_sched_barrier(0);
        #pragma unroll
        for (int ks = 0; ks < 32; ++ks) {
          bf16x8 b0 = *(const bf16x8*)(wbase + (ks * 2 + 0) * 512 + lane * 8);
          bf16x8 b1 = *(const bf16x8*)(wbase + (ks * 2 + 1) * 512 + lane * 8);
          acc00 = mfma16(p0[ks], b0, acc00);
          acc01 = mfma16(p0[ks], b1, acc01);
          acc10 = mfma16(p1[ks], b0, acc10);
          acc11 = mfma16(p1[ks], b1, acc11);
        }
      } else {
        #pragma unroll 4
        for (int ks = 0; ks < 32; ++ks) {
          bf16x8 a0 = lda(A0 + ks * 32 + ko);
          bf16x8 a1 = lda(A1 + ks * 32 + ko);
          bf16x8 b0 = *(const bf16x8*)(wbase + (ks * 2 + 0) * 512 + lane * 8);
          bf16x8 b1 = *(const bf16x8*)(wbase + (ks * 2 + 1) * 512 + lane * 8);
          acc00 = mfma16(a0, b0, acc00);
          acc01 = mfma16(a0, b1, acc01);
          acc10 = mfma16(a1, b0, acc10);
          acc11 = mfma16(a1, b1, acc11);
        }
      }
    }
    if (mat == 0) {
      Xex[(mhalf * 4 + 0) * 64 + lane] = acc00;
      Xex[(mhalf * 4 + 1) * 64 + lane] = acc01;
      Xex[(mhalf * 4 + 2) * 64 + lane] = acc10;
      Xex[(mhalf * 4 + 3) * 64 + lane] = acc11;
    }
    __syncthreads();                               // A: Xex ready
    if (mat == 1) {                                // gates -> c,h -> LDS tile
      #pragma unroll
      for (int mt = 0; mt < 2; ++mt) {
        f32x4 aT0 = mt ? acc10 : acc00;
        f32x4 aT1 = mt ? acc11 : acc01;
        f32x4 gx0 = Xex[(mhalf * 4 + mt * 2 + 0) * 64 + lane];
        f32x4 gx1 = Xex[(mhalf * 4 + mt * 2 + 1) * 64 + lane];
        #pragma unroll
        for (int r = 0; r < 4; ++r) {
          float v0 = aT0[r] + gx0[r];
          float v1 = aT1[r] + gx1[r];
          float p0 = __shfl_xor(v0, 8);
          float p1 = __shfl_xor(v1, 8);
          if ((lane & 15) < 8) {
            float iv = sigm(v0 + b_i);
            float fv = sigm(p0 + b_f);
            float gv = tanh_(v1 + b_g);
            float ov = sigm(p1 + b_o);
            float c  = fv * cst[mt][r] + iv * gv;
            cst[mt][r] = c;
            float h  = ov * tanh_(c);
            int m = mhalf * 32 + mt * 16 + (lane >> 4) * 4 + r;
            Hs[m * 8 + (lane & 15)] = __float2bfloat16(h);
          }
        }
      }
    }
    __syncthreads();                               // B: Hs tile complete
    // flush Hs -> global as 8B agent-coherent (write-through) stores
    if (tid < 128) {
      char* HoutB = (L == 0) ? (char*)(H1 + (((size_t)(t & h1mask)) << 16))
                             : (char*)(H2 + (((size_t)t) << 16));
      u64 v = ((const u64*)Hs)[tid];
      u64* dst = (u64*)(HoutB + ((size_t)(tid >> 1) << 11) + (jg << 4) + ((tid & 1) << 3));
      __hip_atomic_store(dst, v, __ATOMIC_RELAXED, __HIP_MEMORY_SCOPE_AGENT);
    }
    __syncthreads();                               // C: flush drained
    if (wv == 0 && lane == 0)
      __hip_atomic_store(&bar[w], (unsigned)(t + 1),
                         __ATOMIC_RELAXED, __HIP_MEMORY_SCOPE_AGENT);
  }
}

// ---------------------------------------------------------------------------
// K5: R(t,b,n) = H2[t][b][:] @ dec_VT[n][:] + dec_bVT[n]   (bf16)
// ---------------------------------------------------------------------------
__global__ void __launch_bounds__(256) k_dec1(
    const __hip_bfloat16* __restrict__ H2, const __hip_bfloat16* __restrict__ dec_VTC,
    const float* __restrict__ dbv, __hip_bfloat16* __restrict__ R)
{
  const int t = blockIdx.x;
  const int lane = threadIdx.x & 63, wv = threadIdx.x >> 6;
  const __hip_bfloat16* A = H2 + ((size_t)t << 16) + ((size_t)(wv * 16 + (lane & 15)) << 10);
  const int ko = (lane >> 4) * 8;
  f32x4 acc[4];
  for (int i = 0; i < 4; ++i) acc[i] = fzero();
  for (int ks = 0; ks < 32; ++ks) {
    bf16x8 a = *(const bf16x8*)(A + ks * 32 + ko);
    #pragma unroll
    for (int nt = 0; nt < 4; ++nt) {
      bf16x8 b = *(const bf16x8*)(dec_VTC + ((size_t)(nt * 16 + (lane & 15)) << 10) + ks * 32 + ko);
      acc[nt] = mfma16(a, b, acc[nt]);
    }
  }
  #pragma unroll
  for (int nt = 0; nt < 4; ++nt) {
    int n = nt * 16 + (lane & 15);
    float bias = dbv[n];
    #pragma unroll
    for (int r = 0; r < 4; ++r) {
      int b_row = wv * 16 + (lane >> 4) * 4 + r;
      R[((size_t)t << 12) + (size_t)b_row * 64 + n] = __float2bfloat16(acc[nt][r] + bias);
    }
  }
}

// ---------------------------------------------------------------------------
// K6: out[b][v][t] = R(t,b,:) @ dec_U[v][:] + dec_bU[v]; store dtype = mode
// ---------------------------------------------------------------------------
__global__ void __launch_bounds__(256) k_dec2(
    const __hip_bfloat16* __restrict__ R, const __hip_bfloat16* __restrict__ dec_UC,
    const float* __restrict__ dbu, void* __restrict__ out,
    const int* __restrict__ flags)
{
  const int mode = flags[0];
  const int bblk = blockIdx.x >> 4, tblk = blockIdx.x & 15;
  const int lane = threadIdx.x & 63, wv = threadIdx.x >> 6;
  const int ko  = (lane >> 4) * 8;
  const int t_l = lane & 15;
  for (int bi = 0; bi < 4; ++bi) {
    const int b = bblk * 16 + wv * 4 + bi;
    f32x4 acc[16];
    for (int i = 0; i < 16; ++i) acc[i] = fzero();
    #pragma unroll
    for (int ks = 0; ks < 2; ++ks) {
      bf16x8 a = *(const bf16x8*)(R + (((size_t)(tblk * 16 + t_l) * 64 + b) << 6)
                                    + ks * 32 + ko);
      #pragma unroll
      for (int nt = 0; nt < 16; ++nt) {
        bf16x8 bb = *(const bf16x8*)(dec_UC + ((size_t)(nt * 16 + t_l) << 6) + ks * 32 + ko);
        acc[nt] = mfma16(a, bb, acc[nt]);
      }
    }
    #pragma unroll
    for (int nt = 0; nt < 16; ++nt) {
      int v = nt * 16 + t_l;
      float bias = dbu[v];
      size_t off = (size_t)b * 65536 + (size_t)v * 256 + tblk * 16 + (lane >> 4) * 4;
      if (mode) {
        float4 st;
        st.x = acc[nt][0] + bias; st.y = acc[nt][1] + bias;
        st.z = acc[nt][2] + bias; st.w = acc[nt][3] + bias;
        *(float4*)((float*)out + off) = st;
      } else {
        union { bf16x4 v4; __hip_bfloat16 h[4]; } u;
        #pragma unroll
        for (int r = 0; r < 4; ++r) u.h[r] = __float2bfloat16(acc[nt][r] + bias);
        *(bf16x4*)((__hip_bfloat16*)out + off) = u.v4;
      }
    }
  }
}

// ---------------------------------------------------------------------------
extern "C" void kernel_launch(void* const* d_in, const int* in_sizes, int n_in,
                              void* d_out, int out_size, void* d_ws, size_t ws_size,
                              hipStream_t stream)
{
  const int* tokens  = (const int*)d_in[0];
  const void* embed  = d_in[1];
  const void* VT_ih  = d_in[2];
  const void* bVT_ih = d_in[3];
  const void* U_ih   = d_in[4];
  const void* bU_ih  = d_in[5];
  const void* VT_hh  = d_in[6];
  const void* bVT_hh = d_in[7];
  const void* U_hh   = d_in[8];
  const void* bU_hh  = d_in[9];
  const void* dec_VT = d_in[10];
  const void* dec_bVT= d_in[11];
  const void* dec_U  = d_in[12];
  const void* dec_bU = d_in[13];

  char* ws = (char*)d_ws;
  const size_t M = 1024 * 1024;
  // ws layout (100 MB total in big mode, 68 MB in fallback):
  __hip_bfloat16* Wc      = (__hip_bfloat16*)ws;                    // [0,32MB)
  __hip_bfloat16* H2      = (__hip_bfloat16*)(ws + 32 * M);         // [32,64MB)
  char* aux = ws + 64 * M;                                          // [64,68MB)
  int*            flags   = (int*)aux;                              // 256B
  float*          bc      = (float*)(aux + 4096);                   // 32KB
  float*          dbv     = (float*)(aux + 36864);                  // 256B
  float*          dbu     = (float*)(aux + 37120);                  // 1KB
  __hip_bfloat16* embedC  = (__hip_bfloat16*)(aux + 65536);         // 512KB
  __hip_bfloat16* dec_VTC = (__hip_bfloat16*)(aux + 589824);        // 128KB
  __hip_bfloat16* dec_UC  = (__hip_bfloat16*)(aux + 720896);        // 32KB
  __hip_bfloat16* H1ring  = (__hip_bfloat16*)(aux + 1048576);       // 512KB
  unsigned*       bar     = (unsigned*)(aux + 1572864);             // 4KB
  __hip_bfloat16* R       = (__hip_bfloat16*)(aux + 2097152);       // 2MB
  __hip_bfloat16* H1big   = (__hip_bfloat16*)(ws + 68 * M);         // [68,100MB)

  (void)in_sizes; (void)n_in; (void)out_size;

  // big mode: t-unique H1 (fresh addresses) -> all H reads L2-cached
  const int big = (ws_size >= (size_t)100 * M);
  __hip_bfloat16* H1 = big ? H1big : H1ring;
  const int h1mask = big ? 255 : 3;
  const int cmode  = big ? 1 : 0;

  hipFuncSetAttribute((const void*)k_lstm,
                      hipFuncAttributeMaxDynamicSharedMemorySize, 140288);

  k_detect<<<1, 256, 0, stream>>>((const unsigned short*)embed, flags);
  k_cvt_b<<<256, 256, 0, stream>>>(embed,  embedC,  256 * 1024, flags);
  k_cvt_b<<<64,  256, 0, stream>>>(dec_VT, dec_VTC, 64 * 1024,  flags);
  k_cvt_b<<<16,  256, 0, stream>>>(dec_U,  dec_UC,  256 * 64,   flags);
  k_cvt_f<<<1,   64,  0, stream>>>(dec_bVT, dbv, 64,  flags);
  k_cvt_f<<<1,   256, 0, stream>>>(dec_bU,  dbu, 256, flags);
  k_combine<<<4096, 256, 0, stream>>>(U_ih, U_hh, VT_ih, VT_hh, Wc, flags);
  k_bias   <<<2048, 256, 0, stream>>>(bVT_ih, U_ih, bU_ih, bVT_hh, U_hh, bU_hh, bc, flags);
  k_init   <<<1, 256, 0, stream>>>(bar);
  k_lstm   <<<256, 256, 140288, stream>>>(tokens, embedC, Wc, bc, H1, H2, bar,
                                          h1mask, cmode);
  k_dec1   <<<256, 256, 0, stream>>>(H2, dec_VTC, dbv, R);
  k_dec2   <<<64, 256, 0, stream>>>(R, dec_UC, dbu, d_out, flags);
}